// Round 1
// baseline (656.903 us; speedup 1.0000x reference)
//
#include <hip/hip_runtime.h>
#include <math.h>

#define B_ 2
#define N1_ 2048
#define N2_ 512
#define CS_ 384
#define H_ 12
#define PQ_ 8
#define PV_ 12
#define PKV_ 20
#define CQ_ (H_*PQ_*3)    // 288
#define CKV_ (H_*PKV_*3)  // 720
#define INF_ 100000.0f
#define HW_SCALE_ 0.09622504486493764f   // sqrt(1/(3*(PQ*9/2))) = sqrt(1/108)

// ---------------- Q projection: s1 @ Wq, rotate+translate, qn ----------------
__global__ __launch_bounds__(256) void qproj_kernel(
    const float* __restrict__ s1, const float* __restrict__ Wq,
    const float* __restrict__ rot, const float* __restrict__ trans,
    float* __restrict__ qg, float* __restrict__ qn)
{
  __shared__ float srow[CS_];
  __shared__ float proj[CQ_];
  __shared__ float sq[H_*PQ_];
  int row = blockIdx.x;             // b*N1 + i
  int t = threadIdx.x;
  for (int c = t; c < CS_; c += 256) srow[c] = s1[row*CS_ + c];
  __syncthreads();
  for (int col = t; col < CQ_; col += 256) {
    float a0 = 0.f, a1 = 0.f;
    #pragma unroll 8
    for (int c = 0; c < CS_; c += 2) {
      a0 += srow[c]   * Wq[c*CQ_ + col];
      a1 += srow[c+1] * Wq[(c+1)*CQ_ + col];
    }
    proj[col] = a0 + a1;
  }
  __syncthreads();
  if (t < H_*PQ_) {
    const float* R  = rot   + row*9;
    const float* tr = trans + row*3;
    float x = proj[t], y = proj[H_*PQ_ + t], z = proj[2*H_*PQ_ + t];
    float g0 = R[0]*x + R[1]*y + R[2]*z + tr[0];
    float g1 = R[3]*x + R[4]*y + R[5]*z + tr[1];
    float g2 = R[6]*x + R[7]*y + R[8]*z + tr[2];
    int h = t >> 3, p = t & 7;
    int b = row >> 11, i = row & (N1_-1);
    float* dst = qg + (((size_t)(b*H_ + h)*N1_ + i)*PQ_ + p)*3;
    dst[0] = g0; dst[1] = g1; dst[2] = g2;
    sq[t] = g0*g0 + g1*g1 + g2*g2;
  }
  __syncthreads();
  if (t < H_) {
    float s = 0.f;
    #pragma unroll
    for (int p = 0; p < PQ_; ++p) s += sq[t*PQ_ + p];
    int b = row >> 11, i = row & (N1_-1);
    qn[(b*H_ + t)*N1_ + i] = s;
  }
}

// ---------------- KV projection: s2 @ Wkv, rotate+translate, kn ----------------
__global__ __launch_bounds__(256) void kvproj_kernel(
    const float* __restrict__ s2, const float* __restrict__ Wkv,
    const float* __restrict__ rot, const float* __restrict__ trans,
    float* __restrict__ kg, float* __restrict__ vg, float* __restrict__ kn)
{
  __shared__ float srow[CS_];
  __shared__ float proj[CKV_];
  __shared__ float sq[H_*PKV_];
  int row = blockIdx.x;             // b*N2 + j
  int t = threadIdx.x;
  for (int c = t; c < CS_; c += 256) srow[c] = s2[row*CS_ + c];
  __syncthreads();
  for (int col = t; col < CKV_; col += 256) {
    float a0 = 0.f, a1 = 0.f;
    #pragma unroll 8
    for (int c = 0; c < CS_; c += 2) {
      a0 += srow[c]   * Wkv[c*CKV_ + col];
      a1 += srow[c+1] * Wkv[(c+1)*CKV_ + col];
    }
    proj[col] = a0 + a1;
  }
  __syncthreads();
  if (t < H_*PKV_) {
    const float* R  = rot   + row*9;
    const float* tr = trans + row*3;
    float x = proj[t], y = proj[H_*PKV_ + t], z = proj[2*H_*PKV_ + t];
    float g0 = R[0]*x + R[1]*y + R[2]*z + tr[0];
    float g1 = R[3]*x + R[4]*y + R[5]*z + tr[1];
    float g2 = R[6]*x + R[7]*y + R[8]*z + tr[2];
    int h = t / PKV_, p = t % PKV_;
    int b = row >> 9, j = row & (N2_-1);
    if (p < PQ_) {
      float* dst = kg + (((size_t)(b*H_ + h)*N2_ + j)*PQ_ + p)*3;
      dst[0] = g0; dst[1] = g1; dst[2] = g2;
      sq[t] = g0*g0 + g1*g1 + g2*g2;
    } else {
      float* dst = vg + (((size_t)(b*H_ + h)*N2_ + j)*PV_ + (p - PQ_))*3;
      dst[0] = g0; dst[1] = g1; dst[2] = g2;
    }
  }
  __syncthreads();
  if (t < H_) {
    float s = 0.f;
    #pragma unroll
    for (int p = 0; p < PQ_; ++p) s += sq[t*PKV_ + p];
    int b = row >> 9, j = row & (N2_-1);
    kn[(b*H_ + t)*N2_ + j] = s;
  }
}

// ---------------- Fused attention + inverse transform + feats ----------------
// One lane per (b,h,i); wave of 64 consecutive i shares (b,h) -> k/v loads
// are wave-uniform (L1 broadcast). logits <= 0 always => exp safe w/o max.
__global__ __launch_bounds__(64) void attn_kernel(
    const float* __restrict__ qg, const float* __restrict__ qn,
    const float* __restrict__ kg, const float* __restrict__ vg,
    const float* __restrict__ kn, const float* __restrict__ mask1,
    const float* __restrict__ mask2, const float* __restrict__ head_weights,
    const float* __restrict__ rot, const float* __restrict__ trans,
    float* __restrict__ feats)
{
  int blk = blockIdx.x;              // 768 = B*H*(N1/64)
  int iblk = blk & 31;
  int h = (blk >> 5) % H_;
  int b = blk / (32 * H_);
  int lane = threadIdx.x;
  int i = iblk*64 + lane;
  int bh = b*H_ + h;

  // load q (24 floats, 16B-aligned rows)
  const float4* qp = (const float4*)(qg + ((size_t)bh*N1_ + i)*24);
  float q[24];
  #pragma unroll
  for (int r = 0; r < 6; ++r) {
    float4 f = qp[r];
    q[4*r] = f.x; q[4*r+1] = f.y; q[4*r+2] = f.z; q[4*r+3] = f.w;
  }
  float qnn = qn[(size_t)bh*N1_ + i];
  float hw = logf(1.0f + __expf(head_weights[h])) * HW_SCALE_;
  float m1 = mask1[b*N1_ + i];

  float o[36];
  #pragma unroll
  for (int c = 0; c < 36; ++c) o[c] = 0.0f;
  float l = 0.0f;

  const float4* kb = (const float4*)(kg + (size_t)bh*N2_*24);
  const float4* vb = (const float4*)(vg + (size_t)bh*N2_*36);
  const float* knp = kn + (size_t)bh*N2_;
  const float* m2p = mask2 + b*N2_;

  for (int j = 0; j < N2_; ++j) {
    float kk[24];
    #pragma unroll
    for (int r = 0; r < 6; ++r) {
      float4 f = kb[j*6 + r];
      kk[4*r] = f.x; kk[4*r+1] = f.y; kk[4*r+2] = f.z; kk[4*r+3] = f.w;
    }
    float d0 = 0.f, d1 = 0.f, d2a = 0.f, d3 = 0.f;
    #pragma unroll
    for (int c = 0; c < 24; c += 4) {
      d0  += q[c]   * kk[c];
      d1  += q[c+1] * kk[c+1];
      d2a += q[c+2] * kk[c+2];
      d3  += q[c+3] * kk[c+3];
    }
    float dot = (d0 + d1) + (d2a + d3);
    float d2 = qnn + knp[j] - 2.0f * dot;
    float logit = -0.5f * hw * d2 + INF_ * (m1 * m2p[j] - 1.0f);
    float w = __expf(logit);
    l += w;
    #pragma unroll
    for (int r = 0; r < 9; ++r) {
      float4 f = vb[j*9 + r];
      o[4*r]   += w * f.x;
      o[4*r+1] += w * f.y;
      o[4*r+2] += w * f.z;
      o[4*r+3] += w * f.w;
    }
  }

  float inv = 1.0f / l;
  int row = b*N1_ + i;
  const float* R  = rot   + (size_t)row*9;
  const float* tr = trans + (size_t)row*3;
  float R00=R[0],R01=R[1],R02=R[2],R10=R[3],R11=R[4],R12=R[5],R20=R[6],R21=R[7],R22=R[8];
  float t0=tr[0], t1=tr[1], t2=tr[2];
  float* fb = feats + (size_t)row*576 + h*PV_;
  #pragma unroll
  for (int p = 0; p < PV_; ++p) {
    float ox = o[p*3]   * inv - t0;
    float oy = o[p*3+1] * inv - t1;
    float oz = o[p*3+2] * inv - t2;
    // o_loc[n] = sum_m R[m][n] * (o[m]-t[m])   (R^T)
    float lx = R00*ox + R10*oy + R20*oz;
    float ly = R01*ox + R11*oy + R21*oz;
    float lz = R02*ox + R12*oy + R22*oz;
    float dist = sqrtf(lx*lx + ly*ly + lz*lz + 1e-8f);
    fb[p]       = lx;
    fb[144 + p] = ly;
    fb[288 + p] = lz;
    fb[432 + p] = dist;
  }
}

// ---------------- Output projection: feats @ Wout + bout ----------------
__global__ __launch_bounds__(256) void outproj_kernel(
    const float* __restrict__ feats, const float* __restrict__ Wout,
    const float* __restrict__ bout, float* __restrict__ out)
{
  __shared__ float frow[576];
  int row = blockIdx.x;             // b*N1 + i
  int t = threadIdx.x;
  for (int c = t; c < 576; c += 256) frow[c] = feats[(size_t)row*576 + c];
  __syncthreads();
  for (int col = t; col < CS_; col += 256) {
    float a0 = 0.f, a1 = 0.f;
    #pragma unroll 8
    for (int c = 0; c < 576; c += 2) {
      a0 += frow[c]   * Wout[c*CS_ + col];
      a1 += frow[c+1] * Wout[(c+1)*CS_ + col];
    }
    out[(size_t)row*CS_ + col] = a0 + a1 + bout[col];
  }
}

extern "C" void kernel_launch(void* const* d_in, const int* in_sizes, int n_in,
                              void* d_out, int out_size, void* d_ws, size_t ws_size,
                              hipStream_t stream) {
  const float* s1       = (const float*)d_in[0];
  const float* s2       = (const float*)d_in[1];
  const float* r1_rot   = (const float*)d_in[2];
  const float* r1_trans = (const float*)d_in[3];
  const float* r2_rot   = (const float*)d_in[4];
  const float* r2_trans = (const float*)d_in[5];
  const float* mask1    = (const float*)d_in[6];
  const float* mask2    = (const float*)d_in[7];
  const float* Wq       = (const float*)d_in[8];
  const float* Wkv      = (const float*)d_in[9];
  const float* hwts     = (const float*)d_in[10];
  const float* Wout     = (const float*)d_in[11];
  const float* bout     = (const float*)d_in[12];
  float* out = (float*)d_out;

  // workspace partition (all offsets 16B-aligned)
  float* qg    = (float*)d_ws;                       // B*H*N1*24 = 1179648
  float* qn    = qg + (size_t)B_*H_*N1_*24;          // B*H*N1    = 49152
  float* kg    = qn + (size_t)B_*H_*N1_;             // B*H*N2*24 = 294912
  float* vg    = kg + (size_t)B_*H_*N2_*24;          // B*H*N2*36 = 442368
  float* kn    = vg + (size_t)B_*H_*N2_*36;          // B*H*N2    = 12288
  float* feats = kn + (size_t)B_*H_*N2_;             // B*N1*576  = 2359296

  qproj_kernel<<<B_*N1_, 256, 0, stream>>>(s1, Wq, r1_rot, r1_trans, qg, qn);
  kvproj_kernel<<<B_*N2_, 256, 0, stream>>>(s2, Wkv, r2_rot, r2_trans, kg, vg, kn);
  attn_kernel<<<B_*H_*(N1_/64), 64, 0, stream>>>(qg, qn, kg, vg, kn, mask1, mask2,
                                                 hwts, r1_rot, r1_trans, feats);
  outproj_kernel<<<B_*N1_, 256, 0, stream>>>(feats, Wout, bout, out);
}

// Round 2
// 498.771 us; speedup vs baseline: 1.3170x; 1.3170x over previous
//
#include <hip/hip_runtime.h>
#include <math.h>

#define B_ 2
#define N1_ 2048
#define N2_ 512
#define CS_ 384
#define H_ 12
#define PQ_ 8
#define PV_ 12
#define PKV_ 20
#define CQ_ (H_*PQ_*3)    // 288
#define CKV_ (H_*PKV_*3)  // 720
#define INF_ 100000.0f
#define HW_SCALE_ 0.09622504486493764f   // sqrt(1/(3*(PQ*9/2))) = sqrt(1/108)

// ---------------- Q projection: s1 @ Wq, rotate+translate, qn ----------------
__global__ __launch_bounds__(256) void qproj_kernel(
    const float* __restrict__ s1, const float* __restrict__ Wq,
    const float* __restrict__ rot, const float* __restrict__ trans,
    float* __restrict__ qg, float* __restrict__ qn)
{
  __shared__ float srow[CS_];
  __shared__ float proj[CQ_];
  __shared__ float sq[H_*PQ_];
  int row = blockIdx.x;             // b*N1 + i
  int t = threadIdx.x;
  for (int c = t; c < CS_; c += 256) srow[c] = s1[row*CS_ + c];
  __syncthreads();
  for (int col = t; col < CQ_; col += 256) {
    float a0 = 0.f, a1 = 0.f;
    #pragma unroll 8
    for (int c = 0; c < CS_; c += 2) {
      a0 += srow[c]   * Wq[c*CQ_ + col];
      a1 += srow[c+1] * Wq[(c+1)*CQ_ + col];
    }
    proj[col] = a0 + a1;
  }
  __syncthreads();
  if (t < H_*PQ_) {
    const float* R  = rot   + row*9;
    const float* tr = trans + row*3;
    float x = proj[t], y = proj[H_*PQ_ + t], z = proj[2*H_*PQ_ + t];
    float g0 = R[0]*x + R[1]*y + R[2]*z + tr[0];
    float g1 = R[3]*x + R[4]*y + R[5]*z + tr[1];
    float g2 = R[6]*x + R[7]*y + R[8]*z + tr[2];
    int h = t >> 3, p = t & 7;
    int b = row >> 11, i = row & (N1_-1);
    float* dst = qg + (((size_t)(b*H_ + h)*N1_ + i)*PQ_ + p)*3;
    dst[0] = g0; dst[1] = g1; dst[2] = g2;
    sq[t] = g0*g0 + g1*g1 + g2*g2;
  }
  __syncthreads();
  if (t < H_) {
    float s = 0.f;
    #pragma unroll
    for (int p = 0; p < PQ_; ++p) s += sq[t*PQ_ + p];
    int b = row >> 11, i = row & (N1_-1);
    qn[(b*H_ + t)*N1_ + i] = s;
  }
}

// ---------------- KV projection: s2 @ Wkv, rotate+translate, kn ----------------
__global__ __launch_bounds__(256) void kvproj_kernel(
    const float* __restrict__ s2, const float* __restrict__ Wkv,
    const float* __restrict__ rot, const float* __restrict__ trans,
    float* __restrict__ kg, float* __restrict__ vg, float* __restrict__ kn)
{
  __shared__ float srow[CS_];
  __shared__ float proj[CKV_];
  __shared__ float sq[H_*PKV_];
  int row = blockIdx.x;             // b*N2 + j
  int t = threadIdx.x;
  for (int c = t; c < CS_; c += 256) srow[c] = s2[row*CS_ + c];
  __syncthreads();
  for (int col = t; col < CKV_; col += 256) {
    float a0 = 0.f, a1 = 0.f;
    #pragma unroll 8
    for (int c = 0; c < CS_; c += 2) {
      a0 += srow[c]   * Wkv[c*CKV_ + col];
      a1 += srow[c+1] * Wkv[(c+1)*CKV_ + col];
    }
    proj[col] = a0 + a1;
  }
  __syncthreads();
  if (t < H_*PKV_) {
    const float* R  = rot   + row*9;
    const float* tr = trans + row*3;
    float x = proj[t], y = proj[H_*PKV_ + t], z = proj[2*H_*PKV_ + t];
    float g0 = R[0]*x + R[1]*y + R[2]*z + tr[0];
    float g1 = R[3]*x + R[4]*y + R[5]*z + tr[1];
    float g2 = R[6]*x + R[7]*y + R[8]*z + tr[2];
    int h = t / PKV_, p = t % PKV_;
    int b = row >> 9, j = row & (N2_-1);
    if (p < PQ_) {
      float* dst = kg + (((size_t)(b*H_ + h)*N2_ + j)*PQ_ + p)*3;
      dst[0] = g0; dst[1] = g1; dst[2] = g2;
      sq[t] = g0*g0 + g1*g1 + g2*g2;
    } else {
      float* dst = vg + (((size_t)(b*H_ + h)*N2_ + j)*PV_ + (p - PQ_))*3;
      dst[0] = g0; dst[1] = g1; dst[2] = g2;
    }
  }
  __syncthreads();
  if (t < H_) {
    float s = 0.f;
    #pragma unroll
    for (int p = 0; p < PQ_; ++p) s += sq[t*PKV_ + p];
    int b = row >> 9, j = row & (N2_-1);
    kn[(b*H_ + t)*N2_ + j] = s;
  }
}

// ---------------- Fused attention + inverse transform + feats ----------------
// 256 threads = 4 waves per block; block owns 64 consecutive i for one (b,h).
// lane = i, wave w processes j in [w*128, w*128+128). Partial (l, o[36]) are
// linear => exact 2-step LDS tree reduction. logits <= 0 => exp safe w/o max.
#define RED_STRIDE 37   // gcd(37,32)=1 -> conflict-free LDS rows
__global__ __launch_bounds__(256) void attn_kernel(
    const float* __restrict__ qg, const float* __restrict__ qn,
    const float* __restrict__ kg, const float* __restrict__ vg,
    const float* __restrict__ kn, const float* __restrict__ mask1,
    const float* __restrict__ mask2, const float* __restrict__ head_weights,
    const float* __restrict__ rot, const float* __restrict__ trans,
    float* __restrict__ feats)
{
  __shared__ float red[2][64][RED_STRIDE];
  int blk = blockIdx.x;              // 768 = B*H*(N1/64)
  int iblk = blk & 31;
  int h = (blk >> 5) % H_;
  int b = blk / (32 * H_);
  int lane = threadIdx.x & 63;
  int wave = threadIdx.x >> 6;       // 0..3
  int i = iblk*64 + lane;
  int bh = b*H_ + h;

  // load q (24 floats, 16B-aligned rows)
  const float4* qp = (const float4*)(qg + ((size_t)bh*N1_ + i)*24);
  float q[24];
  #pragma unroll
  for (int r = 0; r < 6; ++r) {
    float4 f = qp[r];
    q[4*r] = f.x; q[4*r+1] = f.y; q[4*r+2] = f.z; q[4*r+3] = f.w;
  }
  float qnn = qn[(size_t)bh*N1_ + i];
  float hw = logf(1.0f + __expf(head_weights[h])) * HW_SCALE_;
  float m1 = mask1[b*N1_ + i];

  float o[36];
  #pragma unroll
  for (int c = 0; c < 36; ++c) o[c] = 0.0f;
  float l = 0.0f;

  const float4* kb = (const float4*)(kg + (size_t)bh*N2_*24);
  const float4* vb = (const float4*)(vg + (size_t)bh*N2_*36);
  const float* knp = kn + (size_t)bh*N2_;
  const float* m2p = mask2 + b*N2_;

  const int j0 = wave * (N2_/4);
  #pragma unroll 2
  for (int jj = 0; jj < N2_/4; ++jj) {
    int j = j0 + jj;
    float kk[24];
    #pragma unroll
    for (int r = 0; r < 6; ++r) {
      float4 f = kb[j*6 + r];
      kk[4*r] = f.x; kk[4*r+1] = f.y; kk[4*r+2] = f.z; kk[4*r+3] = f.w;
    }
    float d0 = 0.f, d1 = 0.f, d2a = 0.f, d3 = 0.f;
    #pragma unroll
    for (int c = 0; c < 24; c += 4) {
      d0  += q[c]   * kk[c];
      d1  += q[c+1] * kk[c+1];
      d2a += q[c+2] * kk[c+2];
      d3  += q[c+3] * kk[c+3];
    }
    float dot = (d0 + d1) + (d2a + d3);
    float d2 = qnn + knp[j] - 2.0f * dot;
    float logit = -0.5f * hw * d2 + INF_ * (m1 * m2p[j] - 1.0f);
    float w = __expf(logit);
    l += w;
    #pragma unroll
    for (int r = 0; r < 9; ++r) {
      float4 f = vb[j*9 + r];
      o[4*r]   += w * f.x;
      o[4*r+1] += w * f.y;
      o[4*r+2] += w * f.z;
      o[4*r+3] += w * f.w;
    }
  }

  // ---- tree reduction across 4 waves: (0+2),(1+3) then (0+1) ----
  if (wave >= 2) {
    float* dst = red[wave-2][lane];
    #pragma unroll
    for (int c = 0; c < 36; ++c) dst[c] = o[c];
    dst[36] = l;
  }
  __syncthreads();
  if (wave < 2) {
    const float* src = red[wave][lane];
    #pragma unroll
    for (int c = 0; c < 36; ++c) o[c] += src[c];
    l += src[36];
  }
  __syncthreads();
  if (wave == 1) {
    float* dst = red[0][lane];
    #pragma unroll
    for (int c = 0; c < 36; ++c) dst[c] = o[c];
    dst[36] = l;
  }
  __syncthreads();
  if (wave != 0) return;
  {
    const float* src = red[0][lane];
    #pragma unroll
    for (int c = 0; c < 36; ++c) o[c] += src[c];
    l += src[36];
  }

  float inv = 1.0f / l;
  int row = b*N1_ + i;
  const float* R  = rot   + (size_t)row*9;
  const float* tr = trans + (size_t)row*3;
  float R00=R[0],R01=R[1],R02=R[2],R10=R[3],R11=R[4],R12=R[5],R20=R[6],R21=R[7],R22=R[8];
  float t0=tr[0], t1=tr[1], t2=tr[2];
  float* fb = feats + (size_t)row*576 + h*PV_;
  #pragma unroll
  for (int p = 0; p < PV_; ++p) {
    float ox = o[p*3]   * inv - t0;
    float oy = o[p*3+1] * inv - t1;
    float oz = o[p*3+2] * inv - t2;
    // o_loc[n] = sum_m R[m][n] * (o[m]-t[m])   (R^T)
    float lx = R00*ox + R10*oy + R20*oz;
    float ly = R01*ox + R11*oy + R21*oz;
    float lz = R02*ox + R12*oy + R22*oz;
    float dist = sqrtf(lx*lx + ly*ly + lz*lz + 1e-8f);
    fb[p]       = lx;
    fb[144 + p] = ly;
    fb[288 + p] = lz;
    fb[432 + p] = dist;
  }
}

// ---------------- Output projection: feats @ Wout + bout ----------------
__global__ __launch_bounds__(256) void outproj_kernel(
    const float* __restrict__ feats, const float* __restrict__ Wout,
    const float* __restrict__ bout, float* __restrict__ out)
{
  __shared__ float frow[576];
  int row = blockIdx.x;             // b*N1 + i
  int t = threadIdx.x;
  for (int c = t; c < 576; c += 256) frow[c] = feats[(size_t)row*576 + c];
  __syncthreads();
  for (int col = t; col < CS_; col += 256) {
    float a0 = 0.f, a1 = 0.f;
    #pragma unroll 8
    for (int c = 0; c < 576; c += 2) {
      a0 += frow[c]   * Wout[c*CS_ + col];
      a1 += frow[c+1] * Wout[(c+1)*CS_ + col];
    }
    out[(size_t)row*CS_ + col] = a0 + a1 + bout[col];
  }
}

extern "C" void kernel_launch(void* const* d_in, const int* in_sizes, int n_in,
                              void* d_out, int out_size, void* d_ws, size_t ws_size,
                              hipStream_t stream) {
  const float* s1       = (const float*)d_in[0];
  const float* s2       = (const float*)d_in[1];
  const float* r1_rot   = (const float*)d_in[2];
  const float* r1_trans = (const float*)d_in[3];
  const float* r2_rot   = (const float*)d_in[4];
  const float* r2_trans = (const float*)d_in[5];
  const float* mask1    = (const float*)d_in[6];
  const float* mask2    = (const float*)d_in[7];
  const float* Wq       = (const float*)d_in[8];
  const float* Wkv      = (const float*)d_in[9];
  const float* hwts     = (const float*)d_in[10];
  const float* Wout     = (const float*)d_in[11];
  const float* bout     = (const float*)d_in[12];
  float* out = (float*)d_out;

  // workspace partition (all offsets 16B-aligned)
  float* qg    = (float*)d_ws;                       // B*H*N1*24 = 1179648
  float* qn    = qg + (size_t)B_*H_*N1_*24;          // B*H*N1    = 49152
  float* kg    = qn + (size_t)B_*H_*N1_;             // B*H*N2*24 = 294912
  float* vg    = kg + (size_t)B_*H_*N2_*24;          // B*H*N2*36 = 442368
  float* kn    = vg + (size_t)B_*H_*N2_*36;          // B*H*N2    = 12288
  float* feats = kn + (size_t)B_*H_*N2_;             // B*N1*576  = 2359296

  qproj_kernel<<<B_*N1_, 256, 0, stream>>>(s1, Wq, r1_rot, r1_trans, qg, qn);
  kvproj_kernel<<<B_*N2_, 256, 0, stream>>>(s2, Wkv, r2_rot, r2_trans, kg, vg, kn);
  attn_kernel<<<B_*H_*(N1_/64), 256, 0, stream>>>(qg, qn, kg, vg, kn, mask1, mask2,
                                                  hwts, r1_rot, r1_trans, feats);
  outproj_kernel<<<B_*N1_, 256, 0, stream>>>(feats, Wout, bout, out);
}

// Round 3
// 396.929 us; speedup vs baseline: 1.6550x; 1.2566x over previous
//
#include <hip/hip_runtime.h>
#include <math.h>

#define B_ 2
#define N1_ 2048
#define N2_ 512
#define CS_ 384
#define H_ 12
#define PQ_ 8
#define PV_ 12
#define PKV_ 20
#define CQ_ (H_*PQ_*3)    // 288
#define CKV_ (H_*PKV_*3)  // 720
#define INF_ 100000.0f
#define HW_SCALE_ 0.09622504486493764f   // sqrt(1/(3*(PQ*9/2))) = sqrt(1/108)

// ---------------- Q projection: 8 rows/block, col-per-thread GEMV ----------------
// s-row reads are block-uniform -> scalar loads (s_load) on the scalar pipe;
// weight reads are lane-coalesced; 8 FMAs amortize each weight load.
#define QR_ 8
__global__ __launch_bounds__(320) void qproj_kernel(
    const float* __restrict__ s1, const float* __restrict__ Wq,
    const float* __restrict__ rot, const float* __restrict__ trans,
    float* __restrict__ qg, float* __restrict__ qn)
{
  __shared__ float proj[QR_][CQ_];     // 9216 B
  __shared__ float sq[QR_][H_*PQ_];    // 3072 B
  int row0 = blockIdx.x * QR_;         // rows row0..row0+7 (same b: 2048%8==0)
  int t = threadIdx.x;

  if (t < CQ_) {
    const float* s0 = s1 + (size_t)row0 * CS_;
    float acc[QR_];
    #pragma unroll
    for (int r = 0; r < QR_; ++r) acc[r] = 0.0f;
    const float* wcol = Wq + t;
    #pragma unroll 4
    for (int c = 0; c < CS_; ++c) {
      float w = wcol[(size_t)c * CQ_];
      #pragma unroll
      for (int r = 0; r < QR_; ++r)
        acc[r] += s0[(size_t)r * CS_ + c] * w;
    }
    #pragma unroll
    for (int r = 0; r < QR_; ++r) proj[r][t] = acc[r];
  }
  __syncthreads();

  for (int idx = t; idx < QR_ * 96; idx += 320) {
    int r = idx / 96, p = idx % 96;            // p = h*8 + pq
    int row = row0 + r;
    const float* R  = rot   + (size_t)row*9;
    const float* tr = trans + (size_t)row*3;
    float x = proj[r][p], y = proj[r][96 + p], z = proj[r][192 + p];
    float g0 = R[0]*x + R[1]*y + R[2]*z + tr[0];
    float g1 = R[3]*x + R[4]*y + R[5]*z + tr[1];
    float g2 = R[6]*x + R[7]*y + R[8]*z + tr[2];
    int h = p >> 3, pq = p & 7;
    int b = row >> 11, i = row & (N1_-1);
    float* dst = qg + (((size_t)(b*H_ + h)*N1_ + i)*PQ_ + pq)*3;
    dst[0] = g0; dst[1] = g1; dst[2] = g2;
    sq[r][p] = g0*g0 + g1*g1 + g2*g2;
  }
  __syncthreads();
  if (t < QR_ * H_) {
    int r = t / H_, h = t % H_;
    float s = 0.f;
    #pragma unroll
    for (int p = 0; p < PQ_; ++p) s += sq[r][h*PQ_ + p];
    int row = row0 + r;
    int b = row >> 11, i = row & (N1_-1);
    qn[(b*H_ + h)*N1_ + i] = s;
  }
}

// ---------------- KV projection: 4 rows/block ----------------
#define KVR_ 4
__global__ __launch_bounds__(768) void kvproj_kernel(
    const float* __restrict__ s2, const float* __restrict__ Wkv,
    const float* __restrict__ rot, const float* __restrict__ trans,
    float* __restrict__ kg, float* __restrict__ vg, float* __restrict__ kn)
{
  __shared__ float proj[KVR_][CKV_];       // 11520 B
  __shared__ float sq[KVR_][H_*PKV_];      // 3840 B
  int row0 = blockIdx.x * KVR_;            // 512%4==0 -> same b per block
  int t = threadIdx.x;

  if (t < CKV_) {
    const float* s0 = s2 + (size_t)row0 * CS_;
    float acc[KVR_];
    #pragma unroll
    for (int r = 0; r < KVR_; ++r) acc[r] = 0.0f;
    const float* wcol = Wkv + t;
    #pragma unroll 4
    for (int c = 0; c < CS_; ++c) {
      float w = wcol[(size_t)c * CKV_];
      #pragma unroll
      for (int r = 0; r < KVR_; ++r)
        acc[r] += s0[(size_t)r * CS_ + c] * w;
    }
    #pragma unroll
    for (int r = 0; r < KVR_; ++r) proj[r][t] = acc[r];
  }
  __syncthreads();

  for (int idx = t; idx < KVR_ * 240; idx += 768) {
    int r = idx / 240, p = idx % 240;        // p = h*20 + pp
    int row = row0 + r;
    const float* R  = rot   + (size_t)row*9;
    const float* tr = trans + (size_t)row*3;
    float x = proj[r][p], y = proj[r][240 + p], z = proj[r][480 + p];
    float g0 = R[0]*x + R[1]*y + R[2]*z + tr[0];
    float g1 = R[3]*x + R[4]*y + R[5]*z + tr[1];
    float g2 = R[6]*x + R[7]*y + R[8]*z + tr[2];
    int h = p / PKV_, pp = p % PKV_;
    int b = row >> 9, j = row & (N2_-1);
    if (pp < PQ_) {
      float* dst = kg + (((size_t)(b*H_ + h)*N2_ + j)*PQ_ + pp)*3;
      dst[0] = g0; dst[1] = g1; dst[2] = g2;
      sq[r][p] = g0*g0 + g1*g1 + g2*g2;
    } else {
      float* dst = vg + (((size_t)(b*H_ + h)*N2_ + j)*PV_ + (pp - PQ_))*3;
      dst[0] = g0; dst[1] = g1; dst[2] = g2;
    }
  }
  __syncthreads();
  if (t < KVR_ * H_) {
    int r = t / H_, h = t % H_;
    float s = 0.f;
    #pragma unroll
    for (int p = 0; p < PQ_; ++p) s += sq[r][h*PKV_ + p];
    int row = row0 + r;
    int b = row >> 9, j = row & (N2_-1);
    kn[(b*H_ + h)*N2_ + j] = s;
  }
}

// ---------------- Fused attention + inverse transform + feats ----------------
// 512 threads = 8 waves; block owns 64 consecutive i for one (b,h); wave w
// handles j in [w*64, w*64+64). Linear partials (l,o[36]) -> 3-stage LDS tree.
#define RED_STRIDE 37   // gcd(37,32)=1 -> conflict-free rows
__global__ __launch_bounds__(512) void attn_kernel(
    const float* __restrict__ qg, const float* __restrict__ qn,
    const float* __restrict__ kg, const float* __restrict__ vg,
    const float* __restrict__ kn, const float* __restrict__ mask1,
    const float* __restrict__ mask2, const float* __restrict__ head_weights,
    const float* __restrict__ rot, const float* __restrict__ trans,
    float* __restrict__ feats)
{
  __shared__ float red[4][64][RED_STRIDE];   // 37888 B
  int blk = blockIdx.x;              // 768 = B*H*(N1/64)
  int iblk = blk & 31;
  int h = (blk >> 5) % H_;
  int b = blk / (32 * H_);
  int lane = threadIdx.x & 63;
  int wave = threadIdx.x >> 6;       // 0..7
  int i = iblk*64 + lane;
  int bh = b*H_ + h;

  const float4* qp = (const float4*)(qg + ((size_t)bh*N1_ + i)*24);
  float q[24];
  #pragma unroll
  for (int r = 0; r < 6; ++r) {
    float4 f = qp[r];
    q[4*r] = f.x; q[4*r+1] = f.y; q[4*r+2] = f.z; q[4*r+3] = f.w;
  }
  float qnn = qn[(size_t)bh*N1_ + i];
  float hw = logf(1.0f + __expf(head_weights[h])) * HW_SCALE_;
  float m1 = mask1[b*N1_ + i];

  float o[36];
  #pragma unroll
  for (int c = 0; c < 36; ++c) o[c] = 0.0f;
  float l = 0.0f;

  const float4* kb = (const float4*)(kg + (size_t)bh*N2_*24);
  const float4* vb = (const float4*)(vg + (size_t)bh*N2_*36);
  const float* knp = kn + (size_t)bh*N2_;
  const float* m2p = mask2 + b*N2_;

  const int j0 = wave * (N2_/8);
  #pragma unroll 2
  for (int jj = 0; jj < N2_/8; ++jj) {
    int j = j0 + jj;
    float kk[24];
    #pragma unroll
    for (int r = 0; r < 6; ++r) {
      float4 f = kb[j*6 + r];
      kk[4*r] = f.x; kk[4*r+1] = f.y; kk[4*r+2] = f.z; kk[4*r+3] = f.w;
    }
    float d0 = 0.f, d1 = 0.f, d2a = 0.f, d3 = 0.f;
    #pragma unroll
    for (int c = 0; c < 24; c += 4) {
      d0  += q[c]   * kk[c];
      d1  += q[c+1] * kk[c+1];
      d2a += q[c+2] * kk[c+2];
      d3  += q[c+3] * kk[c+3];
    }
    float dot = (d0 + d1) + (d2a + d3);
    float d2 = qnn + knp[j] - 2.0f * dot;
    float logit = -0.5f * hw * d2 + INF_ * (m1 * m2p[j] - 1.0f);
    float w = __expf(logit);
    l += w;
    #pragma unroll
    for (int r = 0; r < 9; ++r) {
      float4 f = vb[j*9 + r];
      o[4*r]   += w * f.x;
      o[4*r+1] += w * f.y;
      o[4*r+2] += w * f.z;
      o[4*r+3] += w * f.w;
    }
  }

  // ---- 3-stage tree reduction across 8 waves ----
  if (wave >= 4) {
    float* dst = red[wave-4][lane];
    #pragma unroll
    for (int c = 0; c < 36; ++c) dst[c] = o[c];
    dst[36] = l;
  }
  __syncthreads();
  if (wave < 4) {
    const float* src = red[wave][lane];
    #pragma unroll
    for (int c = 0; c < 36; ++c) o[c] += src[c];
    l += src[36];
  }
  __syncthreads();
  if (wave == 2 || wave == 3) {
    float* dst = red[wave-2][lane];
    #pragma unroll
    for (int c = 0; c < 36; ++c) dst[c] = o[c];
    dst[36] = l;
  }
  __syncthreads();
  if (wave < 2) {
    const float* src = red[wave][lane];
    #pragma unroll
    for (int c = 0; c < 36; ++c) o[c] += src[c];
    l += src[36];
  }
  __syncthreads();
  if (wave == 1) {
    float* dst = red[0][lane];
    #pragma unroll
    for (int c = 0; c < 36; ++c) dst[c] = o[c];
    dst[36] = l;
  }
  __syncthreads();
  if (wave != 0) return;
  {
    const float* src = red[0][lane];
    #pragma unroll
    for (int c = 0; c < 36; ++c) o[c] += src[c];
    l += src[36];
  }

  float inv = 1.0f / l;
  int row = b*N1_ + i;
  const float* R  = rot   + (size_t)row*9;
  const float* tr = trans + (size_t)row*3;
  float R00=R[0],R01=R[1],R02=R[2],R10=R[3],R11=R[4],R12=R[5],R20=R[6],R21=R[7],R22=R[8];
  float t0=tr[0], t1=tr[1], t2=tr[2];
  float* fb = feats + (size_t)row*576 + h*PV_;
  #pragma unroll
  for (int p = 0; p < PV_; ++p) {
    float ox = o[p*3]   * inv - t0;
    float oy = o[p*3+1] * inv - t1;
    float oz = o[p*3+2] * inv - t2;
    float lx = R00*ox + R10*oy + R20*oz;
    float ly = R01*ox + R11*oy + R21*oz;
    float lz = R02*ox + R12*oy + R22*oz;
    float dist = sqrtf(lx*lx + ly*ly + lz*lz + 1e-8f);
    fb[p]       = lx;
    fb[144 + p] = ly;
    fb[288 + p] = lz;
    fb[432 + p] = dist;
  }
}

// ---------------- Output projection: 8 rows/block, col-per-thread ----------------
#define OR_ 8
__global__ __launch_bounds__(384) void outproj_kernel(
    const float* __restrict__ feats, const float* __restrict__ Wout,
    const float* __restrict__ bout, float* __restrict__ out)
{
  int row0 = blockIdx.x * OR_;
  int col = threadIdx.x;              // 384 threads = exactly CS_ cols
  const float* f0 = feats + (size_t)row0 * 576;
  float acc[OR_];
  #pragma unroll
  for (int r = 0; r < OR_; ++r) acc[r] = 0.0f;
  const float* wcol = Wout + col;
  #pragma unroll 4
  for (int c = 0; c < 576; ++c) {
    float w = wcol[(size_t)c * CS_];
    #pragma unroll
    for (int r = 0; r < OR_; ++r)
      acc[r] += f0[(size_t)r * 576 + c] * w;
  }
  float bb = bout[col];
  #pragma unroll
  for (int r = 0; r < OR_; ++r)
    out[(size_t)(row0 + r) * CS_ + col] = acc[r] + bb;
}

extern "C" void kernel_launch(void* const* d_in, const int* in_sizes, int n_in,
                              void* d_out, int out_size, void* d_ws, size_t ws_size,
                              hipStream_t stream) {
  const float* s1       = (const float*)d_in[0];
  const float* s2       = (const float*)d_in[1];
  const float* r1_rot   = (const float*)d_in[2];
  const float* r1_trans = (const float*)d_in[3];
  const float* r2_rot   = (const float*)d_in[4];
  const float* r2_trans = (const float*)d_in[5];
  const float* mask1    = (const float*)d_in[6];
  const float* mask2    = (const float*)d_in[7];
  const float* Wq       = (const float*)d_in[8];
  const float* Wkv      = (const float*)d_in[9];
  const float* hwts     = (const float*)d_in[10];
  const float* Wout     = (const float*)d_in[11];
  const float* bout     = (const float*)d_in[12];
  float* out = (float*)d_out;

  float* qg    = (float*)d_ws;                       // B*H*N1*24
  float* qn    = qg + (size_t)B_*H_*N1_*24;          // B*H*N1
  float* kg    = qn + (size_t)B_*H_*N1_;             // B*H*N2*24
  float* vg    = kg + (size_t)B_*H_*N2_*24;          // B*H*N2*36
  float* kn    = vg + (size_t)B_*H_*N2_*36;          // B*H*N2
  float* feats = kn + (size_t)B_*H_*N2_;             // B*N1*576

  qproj_kernel<<<(B_*N1_)/QR_, 320, 0, stream>>>(s1, Wq, r1_rot, r1_trans, qg, qn);
  kvproj_kernel<<<(B_*N2_)/KVR_, 768, 0, stream>>>(s2, Wkv, r2_rot, r2_trans, kg, vg, kn);
  attn_kernel<<<B_*H_*(N1_/64), 512, 0, stream>>>(qg, qn, kg, vg, kn, mask1, mask2,
                                                  hwts, r1_rot, r1_trans, feats);
  outproj_kernel<<<(B_*N1_)/OR_, 384, 0, stream>>>(feats, Wout, bout, out);
}

// Round 4
// 238.275 us; speedup vs baseline: 2.7569x; 1.6658x over previous
//
#include <hip/hip_runtime.h>
#include <math.h>

#define B_ 2
#define N1_ 2048
#define N2_ 512
#define CS_ 384
#define H_ 12
#define PQ_ 8
#define PV_ 12
#define PKV_ 20
#define CQ_ (H_*PQ_*3)    // 288
#define CKV_ (H_*PKV_*3)  // 720
#define INF_ 100000.0f
#define HW_SCALE_ 0.09622504486493764f   // sqrt(1/108)

typedef __attribute__((ext_vector_type(8))) short bf16x8;
typedef __attribute__((ext_vector_type(4))) float f32x4;

__device__ inline unsigned short f2bf(float x) {
  unsigned u = __float_as_uint(x);
  u += 0x7fffu + ((u >> 16) & 1u);      // RNE
  return (unsigned short)(u >> 16);
}

// ---------------- Q projection: 8 rows/block -> bf16 qgb[bh][i][32] + fp32 qn ----------------
#define QR_ 8
__global__ __launch_bounds__(320) void qproj_kernel(
    const float* __restrict__ s1, const float* __restrict__ Wq,
    const float* __restrict__ rot, const float* __restrict__ trans,
    unsigned short* __restrict__ qgb, float* __restrict__ qn)
{
  __shared__ float proj[QR_][CQ_];
  __shared__ float sq[QR_][H_*PQ_];
  int row0 = blockIdx.x * QR_;
  int t = threadIdx.x;

  if (t < CQ_) {
    const float* s0 = s1 + (size_t)row0 * CS_;
    float acc[QR_];
    #pragma unroll
    for (int r = 0; r < QR_; ++r) acc[r] = 0.0f;
    const float* wcol = Wq + t;
    #pragma unroll 4
    for (int c = 0; c < CS_; ++c) {
      float w = wcol[(size_t)c * CQ_];
      #pragma unroll
      for (int r = 0; r < QR_; ++r)
        acc[r] += s0[(size_t)r * CS_ + c] * w;
    }
    #pragma unroll
    for (int r = 0; r < QR_; ++r) proj[r][t] = acc[r];
  }
  __syncthreads();

  for (int idx = t; idx < QR_ * 96; idx += 320) {
    int r = idx / 96, p = idx % 96;            // p = h*8 + pq
    int row = row0 + r;
    const float* R  = rot   + (size_t)row*9;
    const float* tr = trans + (size_t)row*3;
    float x = proj[r][p], y = proj[r][96 + p], z = proj[r][192 + p];
    float g0 = R[0]*x + R[1]*y + R[2]*z + tr[0];
    float g1 = R[3]*x + R[4]*y + R[5]*z + tr[1];
    float g2 = R[6]*x + R[7]*y + R[8]*z + tr[2];
    int h = p >> 3, pq = p & 7;
    int b = row >> 11, i = row & (N1_-1);
    size_t base = ((size_t)(b*H_ + h)*N1_ + i)*32;
    qgb[base + pq*3 + 0] = f2bf(g0);
    qgb[base + pq*3 + 1] = f2bf(g1);
    qgb[base + pq*3 + 2] = f2bf(g2);
    if (pq == 0) {
      #pragma unroll
      for (int c = 24; c < 32; ++c) qgb[base + c] = 0;
    }
    sq[r][p] = g0*g0 + g1*g1 + g2*g2;
  }
  __syncthreads();
  if (t < QR_ * H_) {
    int r = t / H_, h = t % H_;
    float s = 0.f;
    #pragma unroll
    for (int p = 0; p < PQ_; ++p) s += sq[r][h*PQ_ + p];
    int row = row0 + r;
    int b = row >> 11, i = row & (N1_-1);
    qn[(b*H_ + h)*N1_ + i] = s;
  }
}

// ---------------- KV projection -> bf16 kgb[bh][j][32], vtb[bh][48][512], fp32 kn ----------------
#define KVR_ 4
__global__ __launch_bounds__(768) void kvproj_kernel(
    const float* __restrict__ s2, const float* __restrict__ Wkv,
    const float* __restrict__ rot, const float* __restrict__ trans,
    unsigned short* __restrict__ kgb, unsigned short* __restrict__ vtb,
    float* __restrict__ kn)
{
  __shared__ float proj[KVR_][CKV_];
  __shared__ float sq[KVR_][H_*PKV_];
  int row0 = blockIdx.x * KVR_;
  int t = threadIdx.x;

  if (t < CKV_) {
    const float* s0 = s2 + (size_t)row0 * CS_;
    float acc[KVR_];
    #pragma unroll
    for (int r = 0; r < KVR_; ++r) acc[r] = 0.0f;
    const float* wcol = Wkv + t;
    #pragma unroll 4
    for (int c = 0; c < CS_; ++c) {
      float w = wcol[(size_t)c * CKV_];
      #pragma unroll
      for (int r = 0; r < KVR_; ++r)
        acc[r] += s0[(size_t)r * CS_ + c] * w;
    }
    #pragma unroll
    for (int r = 0; r < KVR_; ++r) proj[r][t] = acc[r];
  }
  __syncthreads();

  for (int idx = t; idx < KVR_ * 240; idx += 768) {
    int r = idx / 240, p = idx % 240;        // p = h*20 + pp
    int row = row0 + r;
    const float* R  = rot   + (size_t)row*9;
    const float* tr = trans + (size_t)row*3;
    float x = proj[r][p], y = proj[r][240 + p], z = proj[r][480 + p];
    float g0 = R[0]*x + R[1]*y + R[2]*z + tr[0];
    float g1 = R[3]*x + R[4]*y + R[5]*z + tr[1];
    float g2 = R[6]*x + R[7]*y + R[8]*z + tr[2];
    int h = p / PKV_, pp = p % PKV_;
    int b = row >> 9, j = row & (N2_-1);
    int bh = b*H_ + h;
    if (pp < PQ_) {
      size_t base = ((size_t)bh*N2_ + j)*32;
      kgb[base + pp*3 + 0] = f2bf(g0);
      kgb[base + pp*3 + 1] = f2bf(g1);
      kgb[base + pp*3 + 2] = f2bf(g2);
      if (pp == 0) {
        #pragma unroll
        for (int c = 24; c < 32; ++c) kgb[base + c] = 0;
      }
      sq[r][p] = g0*g0 + g1*g1 + g2*g2;
    } else {
      int comp = (pp - PQ_)*3;
      size_t base = ((size_t)bh*48 + comp)*512 + j;
      vtb[base]        = f2bf(g0);
      vtb[base + 512]  = f2bf(g1);
      vtb[base + 1024] = f2bf(g2);
    }
  }
  // zero-pad vtb comps 36..47 for this block's 4 j's, all 12 h
  {
    int b = row0 >> 9;
    for (int idx = t; idx < KVR_ * H_ * 12; idx += 768) {
      int r = idx / (H_*12);
      int rem = idx % (H_*12);
      int h = rem / 12, cc = rem % 12;
      int j = (row0 + r) & (N2_-1);
      vtb[((size_t)(b*H_ + h)*48 + 36 + cc)*512 + j] = 0;
    }
  }
  __syncthreads();
  if (t < KVR_ * H_) {
    int r = t / H_, h = t % H_;
    float s = 0.f;
    #pragma unroll
    for (int p = 0; p < PQ_; ++p) s += sq[r][h*PKV_ + p];
    int row = row0 + r;
    int b = row >> 9, j = row & (N2_-1);
    kn[(b*H_ + h)*N2_ + j] = s;
  }
}

// ---------------- MFMA flash attention ----------------
// 256 thr = 4 independent waves; wave owns a 16-i tile of one (b,h).
// Per 64-j tile: 4 S-MFMAs (Q·K^T), exp -> bf16 P strip in private LDS,
// 6 PV-MFMAs (O^T = V^T · P^T). No __syncthreads in the main loop.
#define RSTRIDE 72   // bf16/row: 144B, 16B-aligned, 2-way bank alias only
#define OSTRIDE 52
__global__ __launch_bounds__(256) void attn_kernel(
    const unsigned short* __restrict__ qgb, const float* __restrict__ qn,
    const unsigned short* __restrict__ kgb, const unsigned short* __restrict__ vtb,
    const float* __restrict__ kn, const float* __restrict__ mask1,
    const float* __restrict__ mask2, const float* __restrict__ hwts,
    const float* __restrict__ rot, const float* __restrict__ trans,
    float* __restrict__ feats)
{
  __shared__ __align__(16) unsigned short pstrip[4][16][RSTRIDE];
  __shared__ float o_s[4][16][OSTRIDE];
  __shared__ float l_s[4][16];

  int wave = threadIdx.x >> 6;
  int lane = threadIdx.x & 63;
  int col = lane & 15, g = lane >> 4;
  int mt = blockIdx.x*4 + wave;          // 0..3071
  int bh = mt >> 7;                       // /(N1/16)
  int it = mt & 127;
  int b = bh / H_, h = bh - b*H_;

  float hw = logf(1.0f + __expf(hwts[h])) * HW_SCALE_;

  // Q A-fragment: A[m=col][k=g*8+jj]
  bf16x8 qa = *(const bf16x8*)(qgb + (((size_t)bh*N1_ + it*16 + col)*32 + g*8));

  float ar[4], m1r[4];
  #pragma unroll
  for (int r = 0; r < 4; ++r) {
    int ig = it*16 + g*4 + r;
    ar[r]  = fmaf(-0.5f*hw, qn[(size_t)bh*N1_ + ig], -INF_);
    m1r[r] = mask1[b*N1_ + ig] * INF_;
  }

  f32x4 ot[3];
  #pragma unroll
  for (int m = 0; m < 3; ++m) ot[m] = (f32x4){0.f,0.f,0.f,0.f};
  float l[4] = {0.f,0.f,0.f,0.f};

  const unsigned short* kbase = kgb + (size_t)bh*N2_*32;
  const unsigned short* vbase = vtb + (size_t)bh*48*512;
  const float* knp = kn + (size_t)bh*N2_;
  const float* m2p = mask2 + b*N2_;

  for (int jt = 0; jt < 8; ++jt) {
    int j0 = jt*64;
    #pragma unroll
    for (int nt = 0; nt < 4; ++nt) {
      int jg = j0 + nt*16 + col;
      bf16x8 kb = *(const bf16x8*)(kbase + ((size_t)jg*32 + g*8));
      f32x4 dotv = __builtin_amdgcn_mfma_f32_16x16x32_bf16(
          qa, kb, (f32x4){0.f,0.f,0.f,0.f}, 0, 0, 0);
      float bc  = -0.5f*hw*knp[jg];
      float m2c = m2p[jg];
      #pragma unroll
      for (int r = 0; r < 4; ++r) {
        float logit = fmaf(hw, dotv[r], fmaf(m1r[r], m2c, ar[r] + bc));
        float w = __expf(logit);
        l[r] += w;
        pstrip[wave][g*4 + r][nt*16 + col] = f2bf(w);
      }
    }
    // PV: O^T[comp][i] += V^T[comp][j] * P^T[j][i]
    #pragma unroll
    for (int ks = 0; ks < 2; ++ks) {
      bf16x8 pb = *(const bf16x8*)&pstrip[wave][col][ks*32 + g*8];
      #pragma unroll
      for (int mtv = 0; mtv < 3; ++mtv) {
        bf16x8 va = *(const bf16x8*)(vbase +
            ((size_t)(mtv*16 + col))*512 + j0 + ks*32 + g*8);
        ot[mtv] = __builtin_amdgcn_mfma_f32_16x16x32_bf16(va, pb, ot[mtv], 0, 0, 0);
      }
    }
  }

  // row-sum l across the 16 lanes of each quad group
  #pragma unroll
  for (int r = 0; r < 4; ++r) {
    l[r] += __shfl_xor(l[r], 1);
    l[r] += __shfl_xor(l[r], 2);
    l[r] += __shfl_xor(l[r], 4);
    l[r] += __shfl_xor(l[r], 8);
  }
  if (col == 0) {
    #pragma unroll
    for (int r = 0; r < 4; ++r) l_s[wave][g*4 + r] = l[r];
  }
  // O^T -> LDS [i][comp]
  #pragma unroll
  for (int mtv = 0; mtv < 3; ++mtv)
    #pragma unroll
    for (int r = 0; r < 4; ++r)
      o_s[wave][col][mtv*16 + g*4 + r] = ot[mtv][r];
  __syncthreads();

  float inv = 1.0f / l_s[wave][col];
  int ig = it*16 + col;
  int row = b*N1_ + ig;
  const float* R  = rot   + (size_t)row*9;
  const float* tr = trans + (size_t)row*3;
  float R00=R[0],R01=R[1],R02=R[2],R10=R[3],R11=R[4],R12=R[5],R20=R[6],R21=R[7],R22=R[8];
  float t0=tr[0], t1=tr[1], t2=tr[2];
  float* fb = feats + (size_t)row*576 + h*PV_;
  #pragma unroll
  for (int p = 0; p < 3; ++p) {
    int pt = g*3 + p;
    float ox = o_s[wave][col][pt*3+0]*inv - t0;
    float oy = o_s[wave][col][pt*3+1]*inv - t1;
    float oz = o_s[wave][col][pt*3+2]*inv - t2;
    float lx = R00*ox + R10*oy + R20*oz;
    float ly = R01*ox + R11*oy + R21*oz;
    float lz = R02*ox + R12*oy + R22*oz;
    float dist = sqrtf(lx*lx + ly*ly + lz*lz + 1e-8f);
    fb[pt]       = lx;
    fb[144 + pt] = ly;
    fb[288 + pt] = lz;
    fb[432 + pt] = dist;
  }
}

// ---------------- Output projection: 8 rows/block, col-per-thread ----------------
#define OR_ 8
__global__ __launch_bounds__(384) void outproj_kernel(
    const float* __restrict__ feats, const float* __restrict__ Wout,
    const float* __restrict__ bout, float* __restrict__ out)
{
  int row0 = blockIdx.x * OR_;
  int col = threadIdx.x;
  const float* f0 = feats + (size_t)row0 * 576;
  float acc[OR_];
  #pragma unroll
  for (int r = 0; r < OR_; ++r) acc[r] = 0.0f;
  const float* wcol = Wout + col;
  #pragma unroll 4
  for (int c = 0; c < 576; ++c) {
    float w = wcol[(size_t)c * CS_];
    #pragma unroll
    for (int r = 0; r < OR_; ++r)
      acc[r] += f0[(size_t)r * 576 + c] * w;
  }
  float bb = bout[col];
  #pragma unroll
  for (int r = 0; r < OR_; ++r)
    out[(size_t)(row0 + r) * CS_ + col] = acc[r] + bb;
}

extern "C" void kernel_launch(void* const* d_in, const int* in_sizes, int n_in,
                              void* d_out, int out_size, void* d_ws, size_t ws_size,
                              hipStream_t stream) {
  const float* s1       = (const float*)d_in[0];
  const float* s2       = (const float*)d_in[1];
  const float* r1_rot   = (const float*)d_in[2];
  const float* r1_trans = (const float*)d_in[3];
  const float* r2_rot   = (const float*)d_in[4];
  const float* r2_trans = (const float*)d_in[5];
  const float* mask1    = (const float*)d_in[6];
  const float* mask2    = (const float*)d_in[7];
  const float* Wq       = (const float*)d_in[8];
  const float* Wkv      = (const float*)d_in[9];
  const float* hwts     = (const float*)d_in[10];
  const float* Wout     = (const float*)d_in[11];
  const float* bout     = (const float*)d_in[12];
  float* out = (float*)d_out;

  float* qn    = (float*)d_ws;                         // 49152 f32
  float* kn    = qn + (size_t)B_*H_*N1_;               // 12288 f32
  float* feats = kn + (size_t)B_*H_*N2_;               // 2359296 f32
  unsigned short* qgb = (unsigned short*)(feats + (size_t)B_*N1_*576); // B*H*N1*32 u16
  unsigned short* kgb = qgb + (size_t)B_*H_*N1_*32;    // B*H*N2*32 u16
  unsigned short* vtb = kgb + (size_t)B_*H_*N2_*32;    // B*H*48*512 u16

  qproj_kernel<<<(B_*N1_)/QR_, 320, 0, stream>>>(s1, Wq, r1_rot, r1_trans, qgb, qn);
  kvproj_kernel<<<(B_*N2_)/KVR_, 768, 0, stream>>>(s2, Wkv, r2_rot, r2_trans, kgb, vtb, kn);
  attn_kernel<<<(B_*H_*(N1_/16))/4, 256, 0, stream>>>(qgb, qn, kgb, vtb, kn, mask1, mask2,
                                                      hwts, r1_rot, r1_trans, feats);
  outproj_kernel<<<(B_*N1_)/OR_, 384, 0, stream>>>(feats, Wout, bout, out);
}

// Round 5
// 184.887 us; speedup vs baseline: 3.5530x; 1.2888x over previous
//
#include <hip/hip_runtime.h>
#include <math.h>

#define B_ 2
#define N1_ 2048
#define N2_ 512
#define CS_ 384
#define H_ 12
#define PQ_ 8
#define PV_ 12
#define PKV_ 20
#define CQ_ (H_*PQ_*3)    // 288
#define CKV_ (H_*PKV_*3)  // 720
#define INF_ 100000.0f
#define HW_SCALE_ 0.09622504486493764f   // sqrt(1/108)

typedef __attribute__((ext_vector_type(8))) short bf16x8;
typedef __attribute__((ext_vector_type(4))) float f32x4;

__device__ inline unsigned short f2bf(float x) {
  unsigned u = __float_as_uint(x);
  u += 0x7fffu + ((u >> 16) & 1u);      // RNE
  return (unsigned short)(u >> 16);
}

// ---------------- prep: bf16 conversions/transposes + qgb pad ----------------
// blocks [0,1536): s1 -> s1b (4 elts/thread)
// [1536,1968): WqT[n][k] = Wq[k][n]        (110592 elts)
// [1968,2832): WoutT[n][k] = Wout[k][n]    (221184 elts)
// [2832,3024): qgb pad cols 24..31 = 0     (49152 rows)
#define PREP_S1_ 1536
#define PREP_WQ_ 432
#define PREP_WO_ 864
#define PREP_PAD_ 192
__global__ __launch_bounds__(256) void prep_kernel(
    const float* __restrict__ s1, const float* __restrict__ Wq,
    const float* __restrict__ Wout,
    unsigned short* __restrict__ s1b, unsigned short* __restrict__ wqT,
    unsigned short* __restrict__ woutT, unsigned short* __restrict__ qgb)
{
  int blk = blockIdx.x, t = threadIdx.x;
  if (blk < PREP_S1_) {
    int idx = (blk*256 + t) * 4;
    float4 v = *(const float4*)(s1 + idx);
    ushort4 o;
    o.x = f2bf(v.x); o.y = f2bf(v.y); o.z = f2bf(v.z); o.w = f2bf(v.w);
    *(ushort4*)(s1b + idx) = o;
  } else if (blk < PREP_S1_ + PREP_WQ_) {
    int o = (blk - PREP_S1_)*256 + t;
    int n = o / CS_, k = o % CS_;
    wqT[o] = f2bf(Wq[(size_t)k*CQ_ + n]);
  } else if (blk < PREP_S1_ + PREP_WQ_ + PREP_WO_) {
    int o = (blk - PREP_S1_ - PREP_WQ_)*256 + t;
    int n = o / 576, k = o % 576;
    woutT[o] = f2bf(Wout[(size_t)k*CS_ + n]);
  } else {
    int row = (blk - PREP_S1_ - PREP_WQ_ - PREP_WO_)*256 + t;   // 0..49151
    uint4 z = {0u,0u,0u,0u};
    *(uint4*)(qgb + (size_t)row*32 + 24) = z;
  }
}

// ---------------- Q projection via MFMA ----------------
// wave = 16-row strip x rotation triple {nt, nt+6, nt+12}; x,y,z of proj col
// p = nt*16+col land in the same lane -> per-lane rotation. Tile nt covers
// heads 2nt,2nt+1 only -> qn is wave-private (plain store).
__global__ __launch_bounds__(256) void qproj_mfma(
    const unsigned short* __restrict__ s1b, const unsigned short* __restrict__ wqT,
    const float* __restrict__ rot, const float* __restrict__ trans,
    unsigned short* __restrict__ qgb, float* __restrict__ qn)
{
  int wave = threadIdx.x >> 6, lane = threadIdx.x & 63;
  int col = lane & 15, g = lane >> 4;
  int wg = blockIdx.x*4 + wave;        // 0..1535
  int strip = wg / 6;                  // 0..255
  int nt = wg % 6;
  int i0 = strip * 16;

  f32x4 ax = {0.f,0.f,0.f,0.f}, ay = ax, az = ax;
  const unsigned short* arow = s1b + (size_t)(i0 + col)*CS_;
  const unsigned short* bx = wqT + (size_t)((nt     )*16 + col)*CS_;
  const unsigned short* by = wqT + (size_t)((nt +  6)*16 + col)*CS_;
  const unsigned short* bz = wqT + (size_t)((nt + 12)*16 + col)*CS_;
  #pragma unroll
  for (int k = 0; k < CS_; k += 32) {
    bf16x8 a = *(const bf16x8*)(arow + k + g*8);
    ax = __builtin_amdgcn_mfma_f32_16x16x32_bf16(a, *(const bf16x8*)(bx + k + g*8), ax, 0,0,0);
    ay = __builtin_amdgcn_mfma_f32_16x16x32_bf16(a, *(const bf16x8*)(by + k + g*8), ay, 0,0,0);
    az = __builtin_amdgcn_mfma_f32_16x16x32_bf16(a, *(const bf16x8*)(bz + k + g*8), az, 0,0,0);
  }

  int p = nt*16 + col;                 // proj column 0..95
  int h = p >> 3, pq = p & 7;
  float qsum[4];
  #pragma unroll
  for (int r = 0; r < 4; ++r) {
    int row = i0 + g*4 + r;
    const float* R  = rot   + (size_t)row*9;
    const float* tr = trans + (size_t)row*3;
    float x = ax[r], y = ay[r], z = az[r];
    float g0 = R[0]*x + R[1]*y + R[2]*z + tr[0];
    float g1 = R[3]*x + R[4]*y + R[5]*z + tr[1];
    float g2 = R[6]*x + R[7]*y + R[8]*z + tr[2];
    int b = row >> 11, i = row & (N1_-1);
    size_t base = ((size_t)(b*H_ + h)*N1_ + i)*32 + pq*3;
    qgb[base]   = f2bf(g0);
    qgb[base+1] = f2bf(g1);
    qgb[base+2] = f2bf(g2);
    qsum[r] = g0*g0 + g1*g1 + g2*g2;
  }
  // reduce over the 8 cols of each head (xor 1,2,4 stay within 8-lane halves)
  #pragma unroll
  for (int r = 0; r < 4; ++r) {
    qsum[r] += __shfl_xor(qsum[r], 1);
    qsum[r] += __shfl_xor(qsum[r], 2);
    qsum[r] += __shfl_xor(qsum[r], 4);
  }
  if ((col & 7) == 0) {                // col==0 -> h=2nt, col==8 -> h=2nt+1
    int hh = nt*2 + (col >> 3);
    #pragma unroll
    for (int r = 0; r < 4; ++r) {
      int row = i0 + g*4 + r;
      int b = row >> 11, i = row & (N1_-1);
      qn[(size_t)(b*H_ + hh)*N1_ + i] = qsum[r];
    }
  }
}

// ---------------- KV projection (unchanged r3 structure) ----------------
#define KVR_ 4
__global__ __launch_bounds__(768) void kvproj_kernel(
    const float* __restrict__ s2, const float* __restrict__ Wkv,
    const float* __restrict__ rot, const float* __restrict__ trans,
    unsigned short* __restrict__ kgb, unsigned short* __restrict__ vtb,
    float* __restrict__ kn)
{
  __shared__ float proj[KVR_][CKV_];
  __shared__ float sq[KVR_][H_*PKV_];
  int row0 = blockIdx.x * KVR_;
  int t = threadIdx.x;

  if (t < CKV_) {
    const float* s0 = s2 + (size_t)row0 * CS_;
    float acc[KVR_];
    #pragma unroll
    for (int r = 0; r < KVR_; ++r) acc[r] = 0.0f;
    const float* wcol = Wkv + t;
    #pragma unroll 4
    for (int c = 0; c < CS_; ++c) {
      float w = wcol[(size_t)c * CKV_];
      #pragma unroll
      for (int r = 0; r < KVR_; ++r)
        acc[r] += s0[(size_t)r * CS_ + c] * w;
    }
    #pragma unroll
    for (int r = 0; r < KVR_; ++r) proj[r][t] = acc[r];
  }
  __syncthreads();

  for (int idx = t; idx < KVR_ * 240; idx += 768) {
    int r = idx / 240, p = idx % 240;
    int row = row0 + r;
    const float* R  = rot   + (size_t)row*9;
    const float* tr = trans + (size_t)row*3;
    float x = proj[r][p], y = proj[r][240 + p], z = proj[r][480 + p];
    float g0 = R[0]*x + R[1]*y + R[2]*z + tr[0];
    float g1 = R[3]*x + R[4]*y + R[5]*z + tr[1];
    float g2 = R[6]*x + R[7]*y + R[8]*z + tr[2];
    int h = p / PKV_, pp = p % PKV_;
    int b = row >> 9, j = row & (N2_-1);
    int bh = b*H_ + h;
    if (pp < PQ_) {
      size_t base = ((size_t)bh*N2_ + j)*32;
      kgb[base + pp*3 + 0] = f2bf(g0);
      kgb[base + pp*3 + 1] = f2bf(g1);
      kgb[base + pp*3 + 2] = f2bf(g2);
      if (pp == 0) {
        #pragma unroll
        for (int c = 24; c < 32; ++c) kgb[base + c] = 0;
      }
      sq[r][p] = g0*g0 + g1*g1 + g2*g2;
    } else {
      int comp = (pp - PQ_)*3;
      size_t base = ((size_t)bh*48 + comp)*512 + j;
      vtb[base]        = f2bf(g0);
      vtb[base + 512]  = f2bf(g1);
      vtb[base + 1024] = f2bf(g2);
    }
  }
  {
    int b = row0 >> 9;
    for (int idx = t; idx < KVR_ * H_ * 12; idx += 768) {
      int r = idx / (H_*12);
      int rem = idx % (H_*12);
      int h = rem / 12, cc = rem % 12;
      int j = (row0 + r) & (N2_-1);
      vtb[((size_t)(b*H_ + h)*48 + 36 + cc)*512 + j] = 0;
    }
  }
  __syncthreads();
  if (t < KVR_ * H_) {
    int r = t / H_, h = t % H_;
    float s = 0.f;
    #pragma unroll
    for (int p = 0; p < PQ_; ++p) s += sq[r][h*PKV_ + p];
    int row = row0 + r;
    int b = row >> 9, j = row & (N2_-1);
    kn[(b*H_ + h)*N2_ + j] = s;
  }
}

// ---------------- MFMA flash attention (r4, epilogue -> bf16 feats) ----------------
#define RSTRIDE 72
#define OSTRIDE 52
__global__ __launch_bounds__(256) void attn_kernel(
    const unsigned short* __restrict__ qgb, const float* __restrict__ qn,
    const unsigned short* __restrict__ kgb, const unsigned short* __restrict__ vtb,
    const float* __restrict__ kn, const float* __restrict__ mask1,
    const float* __restrict__ mask2, const float* __restrict__ hwts,
    const float* __restrict__ rot, const float* __restrict__ trans,
    unsigned short* __restrict__ featsb)
{
  __shared__ __align__(16) unsigned short pstrip[4][16][RSTRIDE];
  __shared__ float o_s[4][16][OSTRIDE];
  __shared__ float l_s[4][16];

  int wave = threadIdx.x >> 6;
  int lane = threadIdx.x & 63;
  int col = lane & 15, g = lane >> 4;
  int mt = blockIdx.x*4 + wave;
  int bh = mt >> 7;
  int it = mt & 127;
  int b = bh / H_, h = bh - b*H_;

  float hw = logf(1.0f + __expf(hwts[h])) * HW_SCALE_;

  bf16x8 qa = *(const bf16x8*)(qgb + (((size_t)bh*N1_ + it*16 + col)*32 + g*8));

  float ar[4], m1r[4];
  #pragma unroll
  for (int r = 0; r < 4; ++r) {
    int ig = it*16 + g*4 + r;
    ar[r]  = fmaf(-0.5f*hw, qn[(size_t)bh*N1_ + ig], -INF_);
    m1r[r] = mask1[b*N1_ + ig] * INF_;
  }

  f32x4 ot[3];
  #pragma unroll
  for (int m = 0; m < 3; ++m) ot[m] = (f32x4){0.f,0.f,0.f,0.f};
  float l[4] = {0.f,0.f,0.f,0.f};

  const unsigned short* kbase = kgb + (size_t)bh*N2_*32;
  const unsigned short* vbase = vtb + (size_t)bh*48*512;
  const float* knp = kn + (size_t)bh*N2_;
  const float* m2p = mask2 + b*N2_;

  for (int jt = 0; jt < 8; ++jt) {
    int j0 = jt*64;
    #pragma unroll
    for (int nt = 0; nt < 4; ++nt) {
      int jg = j0 + nt*16 + col;
      bf16x8 kb = *(const bf16x8*)(kbase + ((size_t)jg*32 + g*8));
      f32x4 dotv = __builtin_amdgcn_mfma_f32_16x16x32_bf16(
          qa, kb, (f32x4){0.f,0.f,0.f,0.f}, 0, 0, 0);
      float bc  = -0.5f*hw*knp[jg];
      float m2c = m2p[jg];
      #pragma unroll
      for (int r = 0; r < 4; ++r) {
        float logit = fmaf(hw, dotv[r], fmaf(m1r[r], m2c, ar[r] + bc));
        float w = __expf(logit);
        l[r] += w;
        pstrip[wave][g*4 + r][nt*16 + col] = f2bf(w);
      }
    }
    #pragma unroll
    for (int ks = 0; ks < 2; ++ks) {
      bf16x8 pb = *(const bf16x8*)&pstrip[wave][col][ks*32 + g*8];
      #pragma unroll
      for (int mtv = 0; mtv < 3; ++mtv) {
        bf16x8 va = *(const bf16x8*)(vbase +
            ((size_t)(mtv*16 + col))*512 + j0 + ks*32 + g*8);
        ot[mtv] = __builtin_amdgcn_mfma_f32_16x16x32_bf16(va, pb, ot[mtv], 0, 0, 0);
      }
    }
  }

  #pragma unroll
  for (int r = 0; r < 4; ++r) {
    l[r] += __shfl_xor(l[r], 1);
    l[r] += __shfl_xor(l[r], 2);
    l[r] += __shfl_xor(l[r], 4);
    l[r] += __shfl_xor(l[r], 8);
  }
  if (col == 0) {
    #pragma unroll
    for (int r = 0; r < 4; ++r) l_s[wave][g*4 + r] = l[r];
  }
  #pragma unroll
  for (int mtv = 0; mtv < 3; ++mtv)
    #pragma unroll
    for (int r = 0; r < 4; ++r)
      o_s[wave][col][mtv*16 + g*4 + r] = ot[mtv][r];
  __syncthreads();

  float inv = 1.0f / l_s[wave][col];
  int ig = it*16 + col;
  int row = b*N1_ + ig;
  const float* R  = rot   + (size_t)row*9;
  const float* tr = trans + (size_t)row*3;
  float R00=R[0],R01=R[1],R02=R[2],R10=R[3],R11=R[4],R12=R[5],R20=R[6],R21=R[7],R22=R[8];
  float t0=tr[0], t1=tr[1], t2=tr[2];
  unsigned short* fb = featsb + (size_t)row*576 + h*PV_;
  #pragma unroll
  for (int p = 0; p < 3; ++p) {
    int pt = g*3 + p;
    float ox = o_s[wave][col][pt*3+0]*inv - t0;
    float oy = o_s[wave][col][pt*3+1]*inv - t1;
    float oz = o_s[wave][col][pt*3+2]*inv - t2;
    float lx = R00*ox + R10*oy + R20*oz;
    float ly = R01*ox + R11*oy + R21*oz;
    float lz = R02*ox + R12*oy + R22*oz;
    float dist = sqrtf(lx*lx + ly*ly + lz*lz + 1e-8f);
    fb[pt]       = f2bf(lx);
    fb[144 + pt] = f2bf(ly);
    fb[288 + pt] = f2bf(lz);
    fb[432 + pt] = f2bf(dist);
  }
}

// ---------------- Output projection via MFMA ----------------
// wave = 16-row strip x 48 cols (3 tiles); 8 waves/block, 256 blocks.
__global__ __launch_bounds__(512) void outproj_mfma(
    const unsigned short* __restrict__ featsb, const unsigned short* __restrict__ woutT,
    const float* __restrict__ bout, float* __restrict__ out)
{
  int wave = threadIdx.x >> 6, lane = threadIdx.x & 63;
  int col = lane & 15, g = lane >> 4;
  int i0 = blockIdx.x * 16;
  int n0 = wave * 48;

  f32x4 acc[3];
  #pragma unroll
  for (int m = 0; m < 3; ++m) acc[m] = (f32x4){0.f,0.f,0.f,0.f};
  const unsigned short* arow = featsb + (size_t)(i0 + col)*576;
  const unsigned short* b0 = woutT + (size_t)(n0      + col)*576;
  const unsigned short* b1 = woutT + (size_t)(n0 + 16 + col)*576;
  const unsigned short* b2 = woutT + (size_t)(n0 + 32 + col)*576;
  #pragma unroll 3
  for (int k = 0; k < 576; k += 32) {
    bf16x8 a = *(const bf16x8*)(arow + k + g*8);
    acc[0] = __builtin_amdgcn_mfma_f32_16x16x32_bf16(a, *(const bf16x8*)(b0 + k + g*8), acc[0], 0,0,0);
    acc[1] = __builtin_amdgcn_mfma_f32_16x16x32_bf16(a, *(const bf16x8*)(b1 + k + g*8), acc[1], 0,0,0);
    acc[2] = __builtin_amdgcn_mfma_f32_16x16x32_bf16(a, *(const bf16x8*)(b2 + k + g*8), acc[2], 0,0,0);
  }
  #pragma unroll
  for (int t3 = 0; t3 < 3; ++t3) {
    int n = n0 + t3*16 + col;
    float bb = bout[n];
    #pragma unroll
    for (int r = 0; r < 4; ++r) {
      int row = i0 + g*4 + r;
      out[(size_t)row*CS_ + n] = acc[t3][r] + bb;
    }
  }
}

extern "C" void kernel_launch(void* const* d_in, const int* in_sizes, int n_in,
                              void* d_out, int out_size, void* d_ws, size_t ws_size,
                              hipStream_t stream) {
  const float* s1       = (const float*)d_in[0];
  const float* s2       = (const float*)d_in[1];
  const float* r1_rot   = (const float*)d_in[2];
  const float* r1_trans = (const float*)d_in[3];
  const float* r2_rot   = (const float*)d_in[4];
  const float* r2_trans = (const float*)d_in[5];
  const float* mask1    = (const float*)d_in[6];
  const float* mask2    = (const float*)d_in[7];
  const float* Wq       = (const float*)d_in[8];
  const float* Wkv      = (const float*)d_in[9];
  const float* hwts     = (const float*)d_in[10];
  const float* Wout     = (const float*)d_in[11];
  const float* bout     = (const float*)d_in[12];
  float* out = (float*)d_out;

  float* qn = (float*)d_ws;                              // 49152 f32
  float* kn = qn + (size_t)B_*H_*N1_;                    // 12288 f32
  unsigned short* featsb = (unsigned short*)(kn + (size_t)B_*H_*N2_); // 2359296 u16
  unsigned short* qgb  = featsb + (size_t)B_*N1_*576;    // 1572864 u16
  unsigned short* kgb  = qgb  + (size_t)B_*H_*N1_*32;    // 393216 u16
  unsigned short* vtb  = kgb  + (size_t)B_*H_*N2_*32;    // 589824 u16
  unsigned short* s1b  = vtb  + (size_t)B_*H_*48*512;    // 1572864 u16
  unsigned short* wqT  = s1b  + (size_t)B_*N1_*CS_;      // 110592 u16
  unsigned short* woutT= wqT  + (size_t)CQ_*CS_;         // 221184 u16

  prep_kernel<<<PREP_S1_+PREP_WQ_+PREP_WO_+PREP_PAD_, 256, 0, stream>>>(
      s1, Wq, Wout, s1b, wqT, woutT, qgb);
  qproj_mfma<<<384, 256, 0, stream>>>(s1b, wqT, r1_rot, r1_trans, qgb, qn);
  kvproj_kernel<<<(B_*N2_)/KVR_, 768, 0, stream>>>(s2, Wkv, r2_rot, r2_trans, kgb, vtb, kn);
  attn_kernel<<<(B_*H_*(N1_/16))/4, 256, 0, stream>>>(qgb, qn, kgb, vtb, kn, mask1, mask2,
                                                      hwts, r1_rot, r1_trans, featsb);
  outproj_mfma<<<256, 512, 0, stream>>>(featsb, woutT, bout, out);
}

// Round 6
// 163.482 us; speedup vs baseline: 4.0182x; 1.1309x over previous
//
#include <hip/hip_runtime.h>
#include <math.h>

#define B_ 2
#define N1_ 2048
#define N2_ 512
#define CS_ 384
#define H_ 12
#define PQ_ 8
#define PV_ 12
#define PKV_ 20
#define CQ_ (H_*PQ_*3)    // 288
#define CKV_ (H_*PKV_*3)  // 720
#define INF_ 100000.0f
#define HW_SCALE_ 0.09622504486493764f   // sqrt(1/108)

typedef __attribute__((ext_vector_type(8))) short bf16x8;
typedef __attribute__((ext_vector_type(4))) float f32x4;

__device__ inline unsigned short f2bf(float x) {
  unsigned u = __float_as_uint(x);
  u += 0x7fffu + ((u >> 16) & 1u);      // RNE
  return (unsigned short)(u >> 16);
}

// ---------------- prep: bf16 conversions/transposes + pads + kn zero ----------------
#define PREP_S1_  1536   // s1 -> s1b           (1572864 elts, 4/thr)
#define PREP_S2_  384    // s2 -> s2b           (393216 elts, 4/thr)
#define PREP_WQ_  432    // WqT[n][k]=Wq[k][n]  (110592)
#define PREP_WKV_ 1080   // WkvT[n][k]=Wkv[k][n](276480)
#define PREP_WO_  864    // WoutT[n][k]         (221184)
#define PREP_QPAD_ 192   // qgb cols 24..31 = 0 (49152 rows)
#define PREP_VPAD_ 72    // vtb comps 36..47 = 0(147456 elts, 8/thr)
#define PREP_KN_  12     // kn = 0              (12288 f32, 4/thr)
__global__ __launch_bounds__(256) void prep_kernel(
    const float* __restrict__ s1, const float* __restrict__ s2,
    const float* __restrict__ Wq, const float* __restrict__ Wkv,
    const float* __restrict__ Wout,
    unsigned short* __restrict__ s1b, unsigned short* __restrict__ s2b,
    unsigned short* __restrict__ wqT, unsigned short* __restrict__ wkvT,
    unsigned short* __restrict__ woutT, unsigned short* __restrict__ qgb,
    unsigned short* __restrict__ vtb, float* __restrict__ kn)
{
  int blk = blockIdx.x, t = threadIdx.x;
  if (blk < PREP_S1_) {
    int idx = (blk*256 + t) * 4;
    float4 v = *(const float4*)(s1 + idx);
    ushort4 o;
    o.x = f2bf(v.x); o.y = f2bf(v.y); o.z = f2bf(v.z); o.w = f2bf(v.w);
    *(ushort4*)(s1b + idx) = o;
  } else if (blk < PREP_S1_ + PREP_S2_) {
    int idx = ((blk - PREP_S1_)*256 + t) * 4;
    float4 v = *(const float4*)(s2 + idx);
    ushort4 o;
    o.x = f2bf(v.x); o.y = f2bf(v.y); o.z = f2bf(v.z); o.w = f2bf(v.w);
    *(ushort4*)(s2b + idx) = o;
  } else if (blk < PREP_S1_ + PREP_S2_ + PREP_WQ_) {
    int o = (blk - PREP_S1_ - PREP_S2_)*256 + t;
    int n = o / CS_, k = o % CS_;
    wqT[o] = f2bf(Wq[(size_t)k*CQ_ + n]);
  } else if (blk < PREP_S1_ + PREP_S2_ + PREP_WQ_ + PREP_WKV_) {
    int o = (blk - PREP_S1_ - PREP_S2_ - PREP_WQ_)*256 + t;
    int n = o / CS_, k = o % CS_;
    wkvT[o] = f2bf(Wkv[(size_t)k*CKV_ + n]);
  } else if (blk < PREP_S1_ + PREP_S2_ + PREP_WQ_ + PREP_WKV_ + PREP_WO_) {
    int o = (blk - PREP_S1_ - PREP_S2_ - PREP_WQ_ - PREP_WKV_)*256 + t;
    int n = o / 576, k = o % 576;
    woutT[o] = f2bf(Wout[(size_t)k*CS_ + n]);
  } else if (blk < PREP_S1_ + PREP_S2_ + PREP_WQ_ + PREP_WKV_ + PREP_WO_ + PREP_QPAD_) {
    int row = (blk - PREP_S1_ - PREP_S2_ - PREP_WQ_ - PREP_WKV_ - PREP_WO_)*256 + t;
    uint4 z = {0u,0u,0u,0u};
    *(uint4*)(qgb + (size_t)row*32 + 24) = z;
  } else if (blk < PREP_S1_ + PREP_S2_ + PREP_WQ_ + PREP_WKV_ + PREP_WO_ + PREP_QPAD_ + PREP_VPAD_) {
    int idx = (blk - PREP_S1_ - PREP_S2_ - PREP_WQ_ - PREP_WKV_ - PREP_WO_ - PREP_QPAD_)*256 + t;
    int f = idx * 8;                       // 0..147455
    int run = f >> 9, off = f & 511;       // run = bh*12 + (cc-36)
    int bh = run / 12, cc = 36 + run % 12;
    uint4 z = {0u,0u,0u,0u};
    *(uint4*)(vtb + ((size_t)bh*48 + cc)*512 + off) = z;
  } else {
    int idx = (blk - PREP_S1_ - PREP_S2_ - PREP_WQ_ - PREP_WKV_ - PREP_WO_ - PREP_QPAD_ - PREP_VPAD_)*256 + t;
    float4 z = {0.f,0.f,0.f,0.f};
    *(float4*)(kn + (size_t)idx*4) = z;
  }
}

// ---------------- Q projection via MFMA ----------------
__global__ __launch_bounds__(256) void qproj_mfma(
    const unsigned short* __restrict__ s1b, const unsigned short* __restrict__ wqT,
    const float* __restrict__ rot, const float* __restrict__ trans,
    unsigned short* __restrict__ qgb, float* __restrict__ qn)
{
  int wave = threadIdx.x >> 6, lane = threadIdx.x & 63;
  int col = lane & 15, g = lane >> 4;
  int wg = blockIdx.x*4 + wave;        // 0..1535
  int strip = wg / 6;                  // 0..255
  int nt = wg % 6;
  int i0 = strip * 16;

  f32x4 ax = {0.f,0.f,0.f,0.f}, ay = ax, az = ax;
  const unsigned short* arow = s1b + (size_t)(i0 + col)*CS_;
  const unsigned short* bx = wqT + (size_t)((nt     )*16 + col)*CS_;
  const unsigned short* by = wqT + (size_t)((nt +  6)*16 + col)*CS_;
  const unsigned short* bz = wqT + (size_t)((nt + 12)*16 + col)*CS_;
  #pragma unroll
  for (int k = 0; k < CS_; k += 32) {
    bf16x8 a = *(const bf16x8*)(arow + k + g*8);
    ax = __builtin_amdgcn_mfma_f32_16x16x32_bf16(a, *(const bf16x8*)(bx + k + g*8), ax, 0,0,0);
    ay = __builtin_amdgcn_mfma_f32_16x16x32_bf16(a, *(const bf16x8*)(by + k + g*8), ay, 0,0,0);
    az = __builtin_amdgcn_mfma_f32_16x16x32_bf16(a, *(const bf16x8*)(bz + k + g*8), az, 0,0,0);
  }

  int p = nt*16 + col;                 // proj column 0..95
  int h = p >> 3, pq = p & 7;
  float qsum[4];
  #pragma unroll
  for (int r = 0; r < 4; ++r) {
    int row = i0 + g*4 + r;
    const float* R  = rot   + (size_t)row*9;
    const float* tr = trans + (size_t)row*3;
    float x = ax[r], y = ay[r], z = az[r];
    float g0 = R[0]*x + R[1]*y + R[2]*z + tr[0];
    float g1 = R[3]*x + R[4]*y + R[5]*z + tr[1];
    float g2 = R[6]*x + R[7]*y + R[8]*z + tr[2];
    int b = row >> 11, i = row & (N1_-1);
    size_t base = ((size_t)(b*H_ + h)*N1_ + i)*32 + pq*3;
    qgb[base]   = f2bf(g0);
    qgb[base+1] = f2bf(g1);
    qgb[base+2] = f2bf(g2);
    qsum[r] = g0*g0 + g1*g1 + g2*g2;
  }
  #pragma unroll
  for (int r = 0; r < 4; ++r) {
    qsum[r] += __shfl_xor(qsum[r], 1);
    qsum[r] += __shfl_xor(qsum[r], 2);
    qsum[r] += __shfl_xor(qsum[r], 4);
  }
  if ((col & 7) == 0) {
    int hh = nt*2 + (col >> 3);
    #pragma unroll
    for (int r = 0; r < 4; ++r) {
      int row = i0 + g*4 + r;
      int b = row >> 11, i = row & (N1_-1);
      qn[(size_t)(b*H_ + hh)*N1_ + i] = qsum[r];
    }
  }
}

// ---------------- KV projection via MFMA ----------------
// wave = 16-row strip x col-triple {nt, nt+15, nt+30} of WkvT 16-tiles.
// x,y,z of proj col p=nt*16+col in same lane -> per-lane rotation, then
// scatter: pp<8 -> kgb + atomicAdd kn; pp>=8 -> transposed vtb.
__global__ __launch_bounds__(256) void kvproj_mfma(
    const unsigned short* __restrict__ s2b, const unsigned short* __restrict__ wkvT,
    const float* __restrict__ rot, const float* __restrict__ trans,
    unsigned short* __restrict__ kgb, unsigned short* __restrict__ vtb,
    float* __restrict__ kn)
{
  int wave = threadIdx.x >> 6, lane = threadIdx.x & 63;
  int col = lane & 15, g = lane >> 4;
  int wg = blockIdx.x*4 + wave;        // 0..959
  int strip = wg / 15;                 // 0..63
  int nt = wg % 15;                    // 0..14
  int row0 = strip * 16;

  f32x4 ax = {0.f,0.f,0.f,0.f}, ay = ax, az = ax;
  const unsigned short* arow = s2b + (size_t)(row0 + col)*CS_;
  const unsigned short* bx = wkvT + (size_t)(nt*16       + col)*CS_;
  const unsigned short* by = wkvT + (size_t)(nt*16 + 240 + col)*CS_;
  const unsigned short* bz = wkvT + (size_t)(nt*16 + 480 + col)*CS_;
  #pragma unroll
  for (int k = 0; k < CS_; k += 32) {
    bf16x8 a = *(const bf16x8*)(arow + k + g*8);
    ax = __builtin_amdgcn_mfma_f32_16x16x32_bf16(a, *(const bf16x8*)(bx + k + g*8), ax, 0,0,0);
    ay = __builtin_amdgcn_mfma_f32_16x16x32_bf16(a, *(const bf16x8*)(by + k + g*8), ay, 0,0,0);
    az = __builtin_amdgcn_mfma_f32_16x16x32_bf16(a, *(const bf16x8*)(bz + k + g*8), az, 0,0,0);
  }

  int p = nt*16 + col;                 // 0..239
  int h = p / PKV_, pp = p % PKV_;
  #pragma unroll
  for (int r = 0; r < 4; ++r) {
    int row = row0 + g*4 + r;
    const float* R  = rot   + (size_t)row*9;
    const float* tr = trans + (size_t)row*3;
    float x = ax[r], y = ay[r], z = az[r];
    float g0 = R[0]*x + R[1]*y + R[2]*z + tr[0];
    float g1 = R[3]*x + R[4]*y + R[5]*z + tr[1];
    float g2 = R[6]*x + R[7]*y + R[8]*z + tr[2];
    int b = row >> 9, j = row & (N2_-1);
    int bh = b*H_ + h;
    if (pp < PQ_) {
      size_t base = ((size_t)bh*N2_ + j)*32 + pp*3;
      kgb[base]   = f2bf(g0);
      kgb[base+1] = f2bf(g1);
      kgb[base+2] = f2bf(g2);
      if (pp == 0) {
        uint4 z4 = {0u,0u,0u,0u};
        *(uint4*)(kgb + ((size_t)bh*N2_ + j)*32 + 24) = z4;
      }
      atomicAdd(&kn[(size_t)bh*N2_ + j], g0*g0 + g1*g1 + g2*g2);
    } else {
      int comp = (pp - PQ_)*3;
      size_t base = ((size_t)bh*48 + comp)*512 + j;
      vtb[base]        = f2bf(g0);
      vtb[base + 512]  = f2bf(g1);
      vtb[base + 1024] = f2bf(g2);
    }
  }
}

// ---------------- MFMA flash attention ----------------
#define RSTRIDE 72
#define OSTRIDE 52
__global__ __launch_bounds__(256) void attn_kernel(
    const unsigned short* __restrict__ qgb, const float* __restrict__ qn,
    const unsigned short* __restrict__ kgb, const unsigned short* __restrict__ vtb,
    const float* __restrict__ kn, const float* __restrict__ mask1,
    const float* __restrict__ mask2, const float* __restrict__ hwts,
    const float* __restrict__ rot, const float* __restrict__ trans,
    unsigned short* __restrict__ featsb)
{
  __shared__ __align__(16) unsigned short pstrip[4][16][RSTRIDE];
  __shared__ float o_s[4][16][OSTRIDE];
  __shared__ float l_s[4][16];

  int wave = threadIdx.x >> 6;
  int lane = threadIdx.x & 63;
  int col = lane & 15, g = lane >> 4;
  int mt = blockIdx.x*4 + wave;
  int bh = mt >> 7;
  int it = mt & 127;
  int b = bh / H_, h = bh - b*H_;

  float hw = logf(1.0f + __expf(hwts[h])) * HW_SCALE_;

  bf16x8 qa = *(const bf16x8*)(qgb + (((size_t)bh*N1_ + it*16 + col)*32 + g*8));

  float ar[4], m1r[4];
  #pragma unroll
  for (int r = 0; r < 4; ++r) {
    int ig = it*16 + g*4 + r;
    ar[r]  = fmaf(-0.5f*hw, qn[(size_t)bh*N1_ + ig], -INF_);
    m1r[r] = mask1[b*N1_ + ig] * INF_;
  }

  f32x4 ot[3];
  #pragma unroll
  for (int m = 0; m < 3; ++m) ot[m] = (f32x4){0.f,0.f,0.f,0.f};
  float l[4] = {0.f,0.f,0.f,0.f};

  const unsigned short* kbase = kgb + (size_t)bh*N2_*32;
  const unsigned short* vbase = vtb + (size_t)bh*48*512;
  const float* knp = kn + (size_t)bh*N2_;
  const float* m2p = mask2 + b*N2_;

  for (int jt = 0; jt < 8; ++jt) {
    int j0 = jt*64;
    #pragma unroll
    for (int nt = 0; nt < 4; ++nt) {
      int jg = j0 + nt*16 + col;
      bf16x8 kb = *(const bf16x8*)(kbase + ((size_t)jg*32 + g*8));
      f32x4 dotv = __builtin_amdgcn_mfma_f32_16x16x32_bf16(
          qa, kb, (f32x4){0.f,0.f,0.f,0.f}, 0, 0, 0);
      float bc  = -0.5f*hw*knp[jg];
      float m2c = m2p[jg];
      #pragma unroll
      for (int r = 0; r < 4; ++r) {
        float logit = fmaf(hw, dotv[r], fmaf(m1r[r], m2c, ar[r] + bc));
        float w = __expf(logit);
        l[r] += w;
        pstrip[wave][g*4 + r][nt*16 + col] = f2bf(w);
      }
    }
    #pragma unroll
    for (int ks = 0; ks < 2; ++ks) {
      bf16x8 pb = *(const bf16x8*)&pstrip[wave][col][ks*32 + g*8];
      #pragma unroll
      for (int mtv = 0; mtv < 3; ++mtv) {
        bf16x8 va = *(const bf16x8*)(vbase +
            ((size_t)(mtv*16 + col))*512 + j0 + ks*32 + g*8);
        ot[mtv] = __builtin_amdgcn_mfma_f32_16x16x32_bf16(va, pb, ot[mtv], 0, 0, 0);
      }
    }
  }

  #pragma unroll
  for (int r = 0; r < 4; ++r) {
    l[r] += __shfl_xor(l[r], 1);
    l[r] += __shfl_xor(l[r], 2);
    l[r] += __shfl_xor(l[r], 4);
    l[r] += __shfl_xor(l[r], 8);
  }
  if (col == 0) {
    #pragma unroll
    for (int r = 0; r < 4; ++r) l_s[wave][g*4 + r] = l[r];
  }
  #pragma unroll
  for (int mtv = 0; mtv < 3; ++mtv)
    #pragma unroll
    for (int r = 0; r < 4; ++r)
      o_s[wave][col][mtv*16 + g*4 + r] = ot[mtv][r];
  __syncthreads();

  float inv = 1.0f / l_s[wave][col];
  int ig = it*16 + col;
  int row = b*N1_ + ig;
  const float* R  = rot   + (size_t)row*9;
  const float* tr = trans + (size_t)row*3;
  float R00=R[0],R01=R[1],R02=R[2],R10=R[3],R11=R[4],R12=R[5],R20=R[6],R21=R[7],R22=R[8];
  float t0=tr[0], t1=tr[1], t2=tr[2];
  unsigned short* fb = featsb + (size_t)row*576 + h*PV_;
  #pragma unroll
  for (int p = 0; p < 3; ++p) {
    int pt = g*3 + p;
    float ox = o_s[wave][col][pt*3+0]*inv - t0;
    float oy = o_s[wave][col][pt*3+1]*inv - t1;
    float oz = o_s[wave][col][pt*3+2]*inv - t2;
    float lx = R00*ox + R10*oy + R20*oz;
    float ly = R01*ox + R11*oy + R21*oz;
    float lz = R02*ox + R12*oy + R22*oz;
    float dist = sqrtf(lx*lx + ly*ly + lz*lz + 1e-8f);
    fb[pt]       = f2bf(lx);
    fb[144 + pt] = f2bf(ly);
    fb[288 + pt] = f2bf(lz);
    fb[432 + pt] = f2bf(dist);
  }
}

// ---------------- Output projection via MFMA ----------------
__global__ __launch_bounds__(512) void outproj_mfma(
    const unsigned short* __restrict__ featsb, const unsigned short* __restrict__ woutT,
    const float* __restrict__ bout, float* __restrict__ out)
{
  int wave = threadIdx.x >> 6, lane = threadIdx.x & 63;
  int col = lane & 15, g = lane >> 4;
  int i0 = blockIdx.x * 16;
  int n0 = wave * 48;

  f32x4 acc[3];
  #pragma unroll
  for (int m = 0; m < 3; ++m) acc[m] = (f32x4){0.f,0.f,0.f,0.f};
  const unsigned short* arow = featsb + (size_t)(i0 + col)*576;
  const unsigned short* b0 = woutT + (size_t)(n0      + col)*576;
  const unsigned short* b1 = woutT + (size_t)(n0 + 16 + col)*576;
  const unsigned short* b2 = woutT + (size_t)(n0 + 32 + col)*576;
  #pragma unroll 3
  for (int k = 0; k < 576; k += 32) {
    bf16x8 a = *(const bf16x8*)(arow + k + g*8);
    acc[0] = __builtin_amdgcn_mfma_f32_16x16x32_bf16(a, *(const bf16x8*)(b0 + k + g*8), acc[0], 0,0,0);
    acc[1] = __builtin_amdgcn_mfma_f32_16x16x32_bf16(a, *(const bf16x8*)(b1 + k + g*8), acc[1], 0,0,0);
    acc[2] = __builtin_amdgcn_mfma_f32_16x16x32_bf16(a, *(const bf16x8*)(b2 + k + g*8), acc[2], 0,0,0);
  }
  #pragma unroll
  for (int t3 = 0; t3 < 3; ++t3) {
    int n = n0 + t3*16 + col;
    float bb = bout[n];
    #pragma unroll
    for (int r = 0; r < 4; ++r) {
      int row = i0 + g*4 + r;
      out[(size_t)row*CS_ + n] = acc[t3][r] + bb;
    }
  }
}

extern "C" void kernel_launch(void* const* d_in, const int* in_sizes, int n_in,
                              void* d_out, int out_size, void* d_ws, size_t ws_size,
                              hipStream_t stream) {
  const float* s1       = (const float*)d_in[0];
  const float* s2       = (const float*)d_in[1];
  const float* r1_rot   = (const float*)d_in[2];
  const float* r1_trans = (const float*)d_in[3];
  const float* r2_rot   = (const float*)d_in[4];
  const float* r2_trans = (const float*)d_in[5];
  const float* mask1    = (const float*)d_in[6];
  const float* mask2    = (const float*)d_in[7];
  const float* Wq       = (const float*)d_in[8];
  const float* Wkv      = (const float*)d_in[9];
  const float* hwts     = (const float*)d_in[10];
  const float* Wout     = (const float*)d_in[11];
  const float* bout     = (const float*)d_in[12];
  float* out = (float*)d_out;

  float* qn = (float*)d_ws;                              // 49152 f32
  float* kn = qn + (size_t)B_*H_*N1_;                    // 12288 f32
  unsigned short* featsb = (unsigned short*)(kn + (size_t)B_*H_*N2_); // 2359296 u16
  unsigned short* qgb  = featsb + (size_t)B_*N1_*576;    // 1572864 u16
  unsigned short* kgb  = qgb  + (size_t)B_*H_*N1_*32;    // 393216 u16
  unsigned short* vtb  = kgb  + (size_t)B_*H_*N2_*32;    // 589824 u16
  unsigned short* s1b  = vtb  + (size_t)B_*H_*48*512;    // 1572864 u16
  unsigned short* s2b  = s1b  + (size_t)B_*N1_*CS_;      // 393216 u16
  unsigned short* wqT  = s2b  + (size_t)B_*N2_*CS_;      // 110592 u16
  unsigned short* wkvT = wqT  + (size_t)CQ_*CS_;         // 276480 u16
  unsigned short* woutT= wkvT + (size_t)CKV_*CS_;        // 221184 u16

  int prep_blocks = PREP_S1_+PREP_S2_+PREP_WQ_+PREP_WKV_+PREP_WO_+PREP_QPAD_+PREP_VPAD_+PREP_KN_;
  prep_kernel<<<prep_blocks, 256, 0, stream>>>(
      s1, s2, Wq, Wkv, Wout, s1b, s2b, wqT, wkvT, woutT, qgb, vtb, kn);
  qproj_mfma<<<384, 256, 0, stream>>>(s1b, wqT, r1_rot, r1_trans, qgb, qn);
  kvproj_mfma<<<240, 256, 0, stream>>>(s2b, wkvT, r2_rot, r2_trans, kgb, vtb, kn);
  attn_kernel<<<(B_*H_*(N1_/16))/4, 256, 0, stream>>>(qgb, qn, kgb, vtb, kn, mask1, mask2,
                                                      hwts, r1_rot, r1_trans, featsb);
  outproj_mfma<<<256, 512, 0, stream>>>(featsb, woutT, bout, out);
}

// Round 7
// 162.645 us; speedup vs baseline: 4.0389x; 1.0052x over previous
//
#include <hip/hip_runtime.h>
#include <math.h>

#define B_ 2
#define N1_ 2048
#define N2_ 512
#define CS_ 384
#define H_ 12
#define PQ_ 8
#define PV_ 12
#define PKV_ 20
#define CQ_ (H_*PQ_*3)    // 288
#define CKV_ (H_*PKV_*3)  // 720
#define INF_ 100000.0f
#define HW_SCALE_ 0.09622504486493764f   // sqrt(1/108)

typedef __attribute__((ext_vector_type(8))) short bf16x8;
typedef __attribute__((ext_vector_type(4))) float f32x4;

__device__ inline unsigned short f2bf(float x) {
  unsigned u = __float_as_uint(x);
  u += 0x7fffu + ((u >> 16) & 1u);      // RNE
  return (unsigned short)(u >> 16);
}

// convert 8 consecutive f32 -> bf16x8 fragment (two dwordx4 loads)
__device__ inline bf16x8 cvt8(const float* __restrict__ p) {
  float4 a = *(const float4*)p;
  float4 b = *(const float4*)(p + 4);
  bf16x8 r;
  r[0] = (short)f2bf(a.x); r[1] = (short)f2bf(a.y);
  r[2] = (short)f2bf(a.z); r[3] = (short)f2bf(a.w);
  r[4] = (short)f2bf(b.x); r[5] = (short)f2bf(b.y);
  r[6] = (short)f2bf(b.z); r[7] = (short)f2bf(b.w);
  return r;
}

// ---------------- prep: LDS-tiled weight transposes + vtb pad + kn zero ----------------
// 32x32 tiles, coalesced read (over n) and write (over k). K dims all %32==0;
// only Wkv needs an n-guard (720 = 22.5 tiles).
#define TQ_   108   // Wq  384x288: 12 k-tiles x 9 n-tiles
#define TKV_  276   // Wkv 384x720: 12 x 23 (guard n<720)
#define TWO_  216   // Wout 576x384: 18 x 12
#define VPAD_ 72    // vtb comps 36..47 = 0 (147456 elts, 8/thr)
#define KN_   12    // kn = 0 (12288 f32, 4/thr)
__global__ __launch_bounds__(256) void prep_kernel(
    const float* __restrict__ Wq, const float* __restrict__ Wkv,
    const float* __restrict__ Wout,
    unsigned short* __restrict__ wqT, unsigned short* __restrict__ wkvT,
    unsigned short* __restrict__ woutT,
    unsigned short* __restrict__ vtb, float* __restrict__ kn)
{
  __shared__ float lds[32][33];
  int blk = blockIdx.x, t = threadIdx.x;
  int rr0 = t >> 5, cc = t & 31;

  const float* src = nullptr; unsigned short* dst = nullptr;
  int K = 0, N = 0, k0 = 0, n0 = 0;
  if (blk < TQ_) {
    src = Wq; dst = wqT; K = 384; N = CQ_;
    k0 = (blk % 12) * 32; n0 = (blk / 12) * 32;
  } else if (blk < TQ_ + TKV_) {
    int b2 = blk - TQ_;
    src = Wkv; dst = wkvT; K = 384; N = CKV_;
    k0 = (b2 % 12) * 32; n0 = (b2 / 12) * 32;
  } else if (blk < TQ_ + TKV_ + TWO_) {
    int b3 = blk - TQ_ - TKV_;
    src = Wout; dst = woutT; K = 576; N = CS_;
    k0 = (b3 % 18) * 32; n0 = (b3 / 18) * 32;
  } else if (blk < TQ_ + TKV_ + TWO_ + VPAD_) {
    int idx = (blk - TQ_ - TKV_ - TWO_)*256 + t;
    int f = idx * 8;
    int run = f >> 9, off = f & 511;
    int bh = run / 12, cc2 = 36 + run % 12;
    uint4 z = {0u,0u,0u,0u};
    *(uint4*)(vtb + ((size_t)bh*48 + cc2)*512 + off) = z;
    return;
  } else {
    int idx = (blk - TQ_ - TKV_ - TWO_ - VPAD_)*256 + t;
    float4 z = {0.f,0.f,0.f,0.f};
    *(float4*)(kn + (size_t)idx*4) = z;
    return;
  }

  // phase 1: coalesced read W[k0+r][n0+cc]
  #pragma unroll
  for (int rr = 0; rr < 4; ++rr) {
    int r = rr0 + rr*8;
    if (n0 + cc < N) lds[r][cc] = src[(size_t)(k0 + r)*N + n0 + cc];
  }
  __syncthreads();
  // phase 2: coalesced write wT[n0+r][k0+cc] = lds[cc][r]
  #pragma unroll
  for (int rr = 0; rr < 4; ++rr) {
    int r = rr0 + rr*8;
    if (n0 + r < N) dst[(size_t)(n0 + r)*K + k0 + cc] = f2bf(lds[cc][r]);
  }
}

// ---------------- Q projection via MFMA (reads s1 f32 directly) ----------------
__global__ __launch_bounds__(256) void qproj_mfma(
    const float* __restrict__ s1, const unsigned short* __restrict__ wqT,
    const float* __restrict__ rot, const float* __restrict__ trans,
    unsigned short* __restrict__ qgb, float* __restrict__ qn)
{
  int wave = threadIdx.x >> 6, lane = threadIdx.x & 63;
  int col = lane & 15, g = lane >> 4;
  int wg = blockIdx.x*4 + wave;        // 0..1535
  int strip = wg / 6;                  // 0..255
  int nt = wg % 6;
  int i0 = strip * 16;

  f32x4 ax = {0.f,0.f,0.f,0.f}, ay = ax, az = ax;
  const float* arow = s1 + (size_t)(i0 + col)*CS_;
  const unsigned short* bx = wqT + (size_t)((nt     )*16 + col)*CS_;
  const unsigned short* by = wqT + (size_t)((nt +  6)*16 + col)*CS_;
  const unsigned short* bz = wqT + (size_t)((nt + 12)*16 + col)*CS_;
  #pragma unroll
  for (int k = 0; k < CS_; k += 32) {
    bf16x8 a = cvt8(arow + k + g*8);
    ax = __builtin_amdgcn_mfma_f32_16x16x32_bf16(a, *(const bf16x8*)(bx + k + g*8), ax, 0,0,0);
    ay = __builtin_amdgcn_mfma_f32_16x16x32_bf16(a, *(const bf16x8*)(by + k + g*8), ay, 0,0,0);
    az = __builtin_amdgcn_mfma_f32_16x16x32_bf16(a, *(const bf16x8*)(bz + k + g*8), az, 0,0,0);
  }

  int p = nt*16 + col;                 // proj column 0..95
  int h = p >> 3, pq = p & 7;
  float qsum[4];
  #pragma unroll
  for (int r = 0; r < 4; ++r) {
    int row = i0 + g*4 + r;
    const float* R  = rot   + (size_t)row*9;
    const float* tr = trans + (size_t)row*3;
    float x = ax[r], y = ay[r], z = az[r];
    float g0 = R[0]*x + R[1]*y + R[2]*z + tr[0];
    float g1 = R[3]*x + R[4]*y + R[5]*z + tr[1];
    float g2 = R[6]*x + R[7]*y + R[8]*z + tr[2];
    int b = row >> 11, i = row & (N1_-1);
    size_t rbase = ((size_t)(b*H_ + h)*N1_ + i)*32;
    qgb[rbase + pq*3]     = f2bf(g0);
    qgb[rbase + pq*3 + 1] = f2bf(g1);
    qgb[rbase + pq*3 + 2] = f2bf(g2);
    if (pq == 7) {                     // fold pad: cols 24..31 = 0
      uint4 z4 = {0u,0u,0u,0u};
      *(uint4*)(qgb + rbase + 24) = z4;
    }
    qsum[r] = g0*g0 + g1*g1 + g2*g2;
  }
  #pragma unroll
  for (int r = 0; r < 4; ++r) {
    qsum[r] += __shfl_xor(qsum[r], 1);
    qsum[r] += __shfl_xor(qsum[r], 2);
    qsum[r] += __shfl_xor(qsum[r], 4);
  }
  if ((col & 7) == 0) {
    int hh = nt*2 + (col >> 3);
    #pragma unroll
    for (int r = 0; r < 4; ++r) {
      int row = i0 + g*4 + r;
      int b = row >> 11, i = row & (N1_-1);
      qn[(size_t)(b*H_ + hh)*N1_ + i] = qsum[r];
    }
  }
}

// ---------------- KV projection via MFMA (reads s2 f32 directly) ----------------
__global__ __launch_bounds__(256) void kvproj_mfma(
    const float* __restrict__ s2, const unsigned short* __restrict__ wkvT,
    const float* __restrict__ rot, const float* __restrict__ trans,
    unsigned short* __restrict__ kgb, unsigned short* __restrict__ vtb,
    float* __restrict__ kn)
{
  int wave = threadIdx.x >> 6, lane = threadIdx.x & 63;
  int col = lane & 15, g = lane >> 4;
  int wg = blockIdx.x*4 + wave;        // 0..959
  int strip = wg / 15;                 // 0..63
  int nt = wg % 15;                    // 0..14
  int row0 = strip * 16;

  f32x4 ax = {0.f,0.f,0.f,0.f}, ay = ax, az = ax;
  const float* arow = s2 + (size_t)(row0 + col)*CS_;
  const unsigned short* bx = wkvT + (size_t)(nt*16       + col)*CS_;
  const unsigned short* by = wkvT + (size_t)(nt*16 + 240 + col)*CS_;
  const unsigned short* bz = wkvT + (size_t)(nt*16 + 480 + col)*CS_;
  #pragma unroll
  for (int k = 0; k < CS_; k += 32) {
    bf16x8 a = cvt8(arow + k + g*8);
    ax = __builtin_amdgcn_mfma_f32_16x16x32_bf16(a, *(const bf16x8*)(bx + k + g*8), ax, 0,0,0);
    ay = __builtin_amdgcn_mfma_f32_16x16x32_bf16(a, *(const bf16x8*)(by + k + g*8), ay, 0,0,0);
    az = __builtin_amdgcn_mfma_f32_16x16x32_bf16(a, *(const bf16x8*)(bz + k + g*8), az, 0,0,0);
  }

  int p = nt*16 + col;                 // 0..239
  int h = p / PKV_, pp = p % PKV_;
  #pragma unroll
  for (int r = 0; r < 4; ++r) {
    int row = row0 + g*4 + r;
    const float* R  = rot   + (size_t)row*9;
    const float* tr = trans + (size_t)row*3;
    float x = ax[r], y = ay[r], z = az[r];
    float g0 = R[0]*x + R[1]*y + R[2]*z + tr[0];
    float g1 = R[3]*x + R[4]*y + R[5]*z + tr[1];
    float g2 = R[6]*x + R[7]*y + R[8]*z + tr[2];
    int b = row >> 9, j = row & (N2_-1);
    int bh = b*H_ + h;
    if (pp < PQ_) {
      size_t base = ((size_t)bh*N2_ + j)*32 + pp*3;
      kgb[base]   = f2bf(g0);
      kgb[base+1] = f2bf(g1);
      kgb[base+2] = f2bf(g2);
      if (pp == 0) {
        uint4 z4 = {0u,0u,0u,0u};
        *(uint4*)(kgb + ((size_t)bh*N2_ + j)*32 + 24) = z4;
      }
      atomicAdd(&kn[(size_t)bh*N2_ + j], g0*g0 + g1*g1 + g2*g2);
    } else {
      int comp = (pp - PQ_)*3;
      size_t base = ((size_t)bh*48 + comp)*512 + j;
      vtb[base]        = f2bf(g0);
      vtb[base + 512]  = f2bf(g1);
      vtb[base + 1024] = f2bf(g2);
    }
  }
}

// ---------------- MFMA flash attention ----------------
#define RSTRIDE 72
#define OSTRIDE 52
__global__ __launch_bounds__(256) void attn_kernel(
    const unsigned short* __restrict__ qgb, const float* __restrict__ qn,
    const unsigned short* __restrict__ kgb, const unsigned short* __restrict__ vtb,
    const float* __restrict__ kn, const float* __restrict__ mask1,
    const float* __restrict__ mask2, const float* __restrict__ hwts,
    const float* __restrict__ rot, const float* __restrict__ trans,
    unsigned short* __restrict__ featsb)
{
  __shared__ __align__(16) unsigned short pstrip[4][16][RSTRIDE];
  __shared__ float o_s[4][16][OSTRIDE];
  __shared__ float l_s[4][16];

  int wave = threadIdx.x >> 6;
  int lane = threadIdx.x & 63;
  int col = lane & 15, g = lane >> 4;
  int mt = blockIdx.x*4 + wave;
  int bh = mt >> 7;
  int it = mt & 127;
  int b = bh / H_, h = bh - b*H_;

  float hw = logf(1.0f + __expf(hwts[h])) * HW_SCALE_;

  bf16x8 qa = *(const bf16x8*)(qgb + (((size_t)bh*N1_ + it*16 + col)*32 + g*8));

  float ar[4], m1r[4];
  #pragma unroll
  for (int r = 0; r < 4; ++r) {
    int ig = it*16 + g*4 + r;
    ar[r]  = fmaf(-0.5f*hw, qn[(size_t)bh*N1_ + ig], -INF_);
    m1r[r] = mask1[b*N1_ + ig] * INF_;
  }

  f32x4 ot[3];
  #pragma unroll
  for (int m = 0; m < 3; ++m) ot[m] = (f32x4){0.f,0.f,0.f,0.f};
  float l[4] = {0.f,0.f,0.f,0.f};

  const unsigned short* kbase = kgb + (size_t)bh*N2_*32;
  const unsigned short* vbase = vtb + (size_t)bh*48*512;
  const float* knp = kn + (size_t)bh*N2_;
  const float* m2p = mask2 + b*N2_;

  for (int jt = 0; jt < 8; ++jt) {
    int j0 = jt*64;
    #pragma unroll
    for (int nt = 0; nt < 4; ++nt) {
      int jg = j0 + nt*16 + col;
      bf16x8 kb = *(const bf16x8*)(kbase + ((size_t)jg*32 + g*8));
      f32x4 dotv = __builtin_amdgcn_mfma_f32_16x16x32_bf16(
          qa, kb, (f32x4){0.f,0.f,0.f,0.f}, 0, 0, 0);
      float bc  = -0.5f*hw*knp[jg];
      float m2c = m2p[jg];
      #pragma unroll
      for (int r = 0; r < 4; ++r) {
        float logit = fmaf(hw, dotv[r], fmaf(m1r[r], m2c, ar[r] + bc));
        float w = __expf(logit);
        l[r] += w;
        pstrip[wave][g*4 + r][nt*16 + col] = f2bf(w);
      }
    }
    #pragma unroll
    for (int ks = 0; ks < 2; ++ks) {
      bf16x8 pb = *(const bf16x8*)&pstrip[wave][col][ks*32 + g*8];
      #pragma unroll
      for (int mtv = 0; mtv < 3; ++mtv) {
        bf16x8 va = *(const bf16x8*)(vbase +
            ((size_t)(mtv*16 + col))*512 + j0 + ks*32 + g*8);
        ot[mtv] = __builtin_amdgcn_mfma_f32_16x16x32_bf16(va, pb, ot[mtv], 0, 0, 0);
      }
    }
  }

  #pragma unroll
  for (int r = 0; r < 4; ++r) {
    l[r] += __shfl_xor(l[r], 1);
    l[r] += __shfl_xor(l[r], 2);
    l[r] += __shfl_xor(l[r], 4);
    l[r] += __shfl_xor(l[r], 8);
  }
  if (col == 0) {
    #pragma unroll
    for (int r = 0; r < 4; ++r) l_s[wave][g*4 + r] = l[r];
  }
  #pragma unroll
  for (int mtv = 0; mtv < 3; ++mtv)
    #pragma unroll
    for (int r = 0; r < 4; ++r)
      o_s[wave][col][mtv*16 + g*4 + r] = ot[mtv][r];
  __syncthreads();

  float inv = 1.0f / l_s[wave][col];
  int ig = it*16 + col;
  int row = b*N1_ + ig;
  const float* R  = rot   + (size_t)row*9;
  const float* tr = trans + (size_t)row*3;
  float R00=R[0],R01=R[1],R02=R[2],R10=R[3],R11=R[4],R12=R[5],R20=R[6],R21=R[7],R22=R[8];
  float t0=tr[0], t1=tr[1], t2=tr[2];
  unsigned short* fb = featsb + (size_t)row*576 + h*PV_;
  #pragma unroll
  for (int p = 0; p < 3; ++p) {
    int pt = g*3 + p;
    float ox = o_s[wave][col][pt*3+0]*inv - t0;
    float oy = o_s[wave][col][pt*3+1]*inv - t1;
    float oz = o_s[wave][col][pt*3+2]*inv - t2;
    float lx = R00*ox + R10*oy + R20*oz;
    float ly = R01*ox + R11*oy + R21*oz;
    float lz = R02*ox + R12*oy + R22*oz;
    float dist = sqrtf(lx*lx + ly*ly + lz*lz + 1e-8f);
    fb[pt]       = f2bf(lx);
    fb[144 + pt] = f2bf(ly);
    fb[288 + pt] = f2bf(lz);
    fb[432 + pt] = f2bf(dist);
  }
}

// ---------------- Output projection via MFMA ----------------
__global__ __launch_bounds__(512) void outproj_mfma(
    const unsigned short* __restrict__ featsb, const unsigned short* __restrict__ woutT,
    const float* __restrict__ bout, float* __restrict__ out)
{
  int wave = threadIdx.x >> 6, lane = threadIdx.x & 63;
  int col = lane & 15, g = lane >> 4;
  int i0 = blockIdx.x * 16;
  int n0 = wave * 48;

  f32x4 acc[3];
  #pragma unroll
  for (int m = 0; m < 3; ++m) acc[m] = (f32x4){0.f,0.f,0.f,0.f};
  const unsigned short* arow = featsb + (size_t)(i0 + col)*576;
  const unsigned short* b0 = woutT + (size_t)(n0      + col)*576;
  const unsigned short* b1 = woutT + (size_t)(n0 + 16 + col)*576;
  const unsigned short* b2 = woutT + (size_t)(n0 + 32 + col)*576;
  #pragma unroll 3
  for (int k = 0; k < 576; k += 32) {
    bf16x8 a = *(const bf16x8*)(arow + k + g*8);
    acc[0] = __builtin_amdgcn_mfma_f32_16x16x32_bf16(a, *(const bf16x8*)(b0 + k + g*8), acc[0], 0,0,0);
    acc[1] = __builtin_amdgcn_mfma_f32_16x16x32_bf16(a, *(const bf16x8*)(b1 + k + g*8), acc[1], 0,0,0);
    acc[2] = __builtin_amdgcn_mfma_f32_16x16x32_bf16(a, *(const bf16x8*)(b2 + k + g*8), acc[2], 0,0,0);
  }
  #pragma unroll
  for (int t3 = 0; t3 < 3; ++t3) {
    int n = n0 + t3*16 + col;
    float bb = bout[n];
    #pragma unroll
    for (int r = 0; r < 4; ++r) {
      int row = i0 + g*4 + r;
      out[(size_t)row*CS_ + n] = acc[t3][r] + bb;
    }
  }
}

extern "C" void kernel_launch(void* const* d_in, const int* in_sizes, int n_in,
                              void* d_out, int out_size, void* d_ws, size_t ws_size,
                              hipStream_t stream) {
  const float* s1       = (const float*)d_in[0];
  const float* s2       = (const float*)d_in[1];
  const float* r1_rot   = (const float*)d_in[2];
  const float* r1_trans = (const float*)d_in[3];
  const float* r2_rot   = (const float*)d_in[4];
  const float* r2_trans = (const float*)d_in[5];
  const float* mask1    = (const float*)d_in[6];
  const float* mask2    = (const float*)d_in[7];
  const float* Wq       = (const float*)d_in[8];
  const float* Wkv      = (const float*)d_in[9];
  const float* hwts     = (const float*)d_in[10];
  const float* Wout     = (const float*)d_in[11];
  const float* bout     = (const float*)d_in[12];
  float* out = (float*)d_out;

  float* qn = (float*)d_ws;                              // 49152 f32
  float* kn = qn + (size_t)B_*H_*N1_;                    // 12288 f32
  unsigned short* featsb = (unsigned short*)(kn + (size_t)B_*H_*N2_); // 2359296 u16
  unsigned short* qgb  = featsb + (size_t)B_*N1_*576;    // 1572864 u16
  unsigned short* kgb  = qgb  + (size_t)B_*H_*N1_*32;    // 393216 u16
  unsigned short* vtb  = kgb  + (size_t)B_*H_*N2_*32;    // 589824 u16
  unsigned short* wqT  = vtb  + (size_t)B_*H_*48*512;    // 110592 u16
  unsigned short* wkvT = wqT  + (size_t)CQ_*CS_;         // 276480 u16
  unsigned short* woutT= wkvT + (size_t)CKV_*CS_;        // 221184 u16

  prep_kernel<<<TQ_+TKV_+TWO_+VPAD_+KN_, 256, 0, stream>>>(
      Wq, Wkv, Wout, wqT, wkvT, woutT, vtb, kn);
  qproj_mfma<<<384, 256, 0, stream>>>(s1, wqT, r1_rot, r1_trans, qgb, qn);
  kvproj_mfma<<<240, 256, 0, stream>>>(s2, wkvT, r2_rot, r2_trans, kgb, vtb, kn);
  attn_kernel<<<(B_*H_*(N1_/16))/4, 256, 0, stream>>>(qgb, qn, kgb, vtb, kn, mask1, mask2,
                                                      hwts, r1_rot, r1_trans, featsb);
  outproj_mfma<<<256, 512, 0, stream>>>(featsb, woutT, bout, out);
}

// Round 8
// 158.277 us; speedup vs baseline: 4.1503x; 1.0276x over previous
//
#include <hip/hip_runtime.h>
#include <math.h>

#define B_ 2
#define N1_ 2048
#define N2_ 512
#define CS_ 384
#define H_ 12
#define PQ_ 8
#define PV_ 12
#define PKV_ 20
#define CQ_ (H_*PQ_*3)    // 288
#define CKV_ (H_*PKV_*3)  // 720
#define INF_ 100000.0f
#define HW_SCALE_ 0.09622504486493764f   // sqrt(1/108)

typedef __attribute__((ext_vector_type(8))) short bf16x8;
typedef __attribute__((ext_vector_type(4))) float f32x4;

__device__ inline unsigned short f2bf(float x) {
  unsigned u = __float_as_uint(x);
  u += 0x7fffu + ((u >> 16) & 1u);      // RNE
  return (unsigned short)(u >> 16);
}

// convert 8 consecutive f32 -> bf16x8 fragment (two dwordx4 loads)
__device__ inline bf16x8 cvt8(const float* __restrict__ p) {
  float4 a = *(const float4*)p;
  float4 b = *(const float4*)(p + 4);
  bf16x8 r;
  r[0] = (short)f2bf(a.x); r[1] = (short)f2bf(a.y);
  r[2] = (short)f2bf(a.z); r[3] = (short)f2bf(a.w);
  r[4] = (short)f2bf(b.x); r[5] = (short)f2bf(b.y);
  r[6] = (short)f2bf(b.z); r[7] = (short)f2bf(b.w);
  return r;
}

// ---------------- prep: LDS-tiled weight transposes + vtb pad + kn zero ----------------
#define TQ_   108   // Wq  384x288: 12 k-tiles x 9 n-tiles
#define TKV_  276   // Wkv 384x720: 12 x 23 (guard n<720)
#define TWO_  216   // Wout 576x384: 18 x 12
#define VPAD_ 72    // vtb comps 36..47 = 0 (147456 elts, 8/thr)
#define KN_   12    // kn = 0 (12288 f32, 4/thr)
__global__ __launch_bounds__(256) void prep_kernel(
    const float* __restrict__ Wq, const float* __restrict__ Wkv,
    const float* __restrict__ Wout,
    unsigned short* __restrict__ wqT, unsigned short* __restrict__ wkvT,
    unsigned short* __restrict__ woutT,
    unsigned short* __restrict__ vtb, float* __restrict__ kn)
{
  __shared__ float lds[32][33];
  int blk = blockIdx.x, t = threadIdx.x;
  int rr0 = t >> 5, cc = t & 31;

  const float* src = nullptr; unsigned short* dst = nullptr;
  int K = 0, N = 0, k0 = 0, n0 = 0;
  if (blk < TQ_) {
    src = Wq; dst = wqT; K = 384; N = CQ_;
    k0 = (blk % 12) * 32; n0 = (blk / 12) * 32;
  } else if (blk < TQ_ + TKV_) {
    int b2 = blk - TQ_;
    src = Wkv; dst = wkvT; K = 384; N = CKV_;
    k0 = (b2 % 12) * 32; n0 = (b2 / 12) * 32;
  } else if (blk < TQ_ + TKV_ + TWO_) {
    int b3 = blk - TQ_ - TKV_;
    src = Wout; dst = woutT; K = 576; N = CS_;
    k0 = (b3 % 18) * 32; n0 = (b3 / 18) * 32;
  } else if (blk < TQ_ + TKV_ + TWO_ + VPAD_) {
    int idx = (blk - TQ_ - TKV_ - TWO_)*256 + t;
    int f = idx * 8;
    int run = f >> 9, off = f & 511;
    int bh = run / 12, cc2 = 36 + run % 12;
    uint4 z = {0u,0u,0u,0u};
    *(uint4*)(vtb + ((size_t)bh*48 + cc2)*512 + off) = z;
    return;
  } else {
    int idx = (blk - TQ_ - TKV_ - TWO_ - VPAD_)*256 + t;
    float4 z = {0.f,0.f,0.f,0.f};
    *(float4*)(kn + (size_t)idx*4) = z;
    return;
  }

  #pragma unroll
  for (int rr = 0; rr < 4; ++rr) {
    int r = rr0 + rr*8;
    if (n0 + cc < N) lds[r][cc] = src[(size_t)(k0 + r)*N + n0 + cc];
  }
  __syncthreads();
  #pragma unroll
  for (int rr = 0; rr < 4; ++rr) {
    int r = rr0 + rr*8;
    if (n0 + r < N) dst[(size_t)(n0 + r)*K + k0 + cc] = f2bf(lds[cc][r]);
  }
}

// ---------------- fused Q + KV projection via MFMA ----------------
// blocks [0,384): qproj; [384,624): kvproj. Independent work co-resident.
__global__ __launch_bounds__(256) void proj_mfma(
    const float* __restrict__ s1, const float* __restrict__ s2,
    const unsigned short* __restrict__ wqT, const unsigned short* __restrict__ wkvT,
    const float* __restrict__ r1_rot, const float* __restrict__ r1_trans,
    const float* __restrict__ r2_rot, const float* __restrict__ r2_trans,
    unsigned short* __restrict__ qgb, float* __restrict__ qn,
    unsigned short* __restrict__ kgb, unsigned short* __restrict__ vtb,
    float* __restrict__ kn)
{
  int wave = threadIdx.x >> 6, lane = threadIdx.x & 63;
  int col = lane & 15, g = lane >> 4;

  if (blockIdx.x < 384) {
    // ---- Q projection ----
    int wg = blockIdx.x*4 + wave;        // 0..1535
    int strip = wg / 6;                  // 0..255
    int nt = wg % 6;
    int i0 = strip * 16;

    f32x4 ax = {0.f,0.f,0.f,0.f}, ay = ax, az = ax;
    const float* arow = s1 + (size_t)(i0 + col)*CS_;
    const unsigned short* bx = wqT + (size_t)((nt     )*16 + col)*CS_;
    const unsigned short* by = wqT + (size_t)((nt +  6)*16 + col)*CS_;
    const unsigned short* bz = wqT + (size_t)((nt + 12)*16 + col)*CS_;
    #pragma unroll
    for (int k = 0; k < CS_; k += 32) {
      bf16x8 a = cvt8(arow + k + g*8);
      ax = __builtin_amdgcn_mfma_f32_16x16x32_bf16(a, *(const bf16x8*)(bx + k + g*8), ax, 0,0,0);
      ay = __builtin_amdgcn_mfma_f32_16x16x32_bf16(a, *(const bf16x8*)(by + k + g*8), ay, 0,0,0);
      az = __builtin_amdgcn_mfma_f32_16x16x32_bf16(a, *(const bf16x8*)(bz + k + g*8), az, 0,0,0);
    }

    int p = nt*16 + col;
    int h = p >> 3, pq = p & 7;
    float qsum[4];
    #pragma unroll
    for (int r = 0; r < 4; ++r) {
      int row = i0 + g*4 + r;
      const float* R  = r1_rot   + (size_t)row*9;
      const float* tr = r1_trans + (size_t)row*3;
      float x = ax[r], y = ay[r], z = az[r];
      float g0 = R[0]*x + R[1]*y + R[2]*z + tr[0];
      float g1 = R[3]*x + R[4]*y + R[5]*z + tr[1];
      float g2 = R[6]*x + R[7]*y + R[8]*z + tr[2];
      int b = row >> 11, i = row & (N1_-1);
      size_t rbase = ((size_t)(b*H_ + h)*N1_ + i)*32;
      qgb[rbase + pq*3]     = f2bf(g0);
      qgb[rbase + pq*3 + 1] = f2bf(g1);
      qgb[rbase + pq*3 + 2] = f2bf(g2);
      if (pq == 7) {
        uint4 z4 = {0u,0u,0u,0u};
        *(uint4*)(qgb + rbase + 24) = z4;
      }
      qsum[r] = g0*g0 + g1*g1 + g2*g2;
    }
    #pragma unroll
    for (int r = 0; r < 4; ++r) {
      qsum[r] += __shfl_xor(qsum[r], 1);
      qsum[r] += __shfl_xor(qsum[r], 2);
      qsum[r] += __shfl_xor(qsum[r], 4);
    }
    if ((col & 7) == 0) {
      int hh = nt*2 + (col >> 3);
      #pragma unroll
      for (int r = 0; r < 4; ++r) {
        int row = i0 + g*4 + r;
        int b = row >> 11, i = row & (N1_-1);
        qn[(size_t)(b*H_ + hh)*N1_ + i] = qsum[r];
      }
    }
  } else {
    // ---- KV projection ----
    int wg = (blockIdx.x - 384)*4 + wave;  // 0..959
    int strip = wg / 15;                   // 0..63
    int nt = wg % 15;                      // 0..14
    int row0 = strip * 16;

    f32x4 ax = {0.f,0.f,0.f,0.f}, ay = ax, az = ax;
    const float* arow = s2 + (size_t)(row0 + col)*CS_;
    const unsigned short* bx = wkvT + (size_t)(nt*16       + col)*CS_;
    const unsigned short* by = wkvT + (size_t)(nt*16 + 240 + col)*CS_;
    const unsigned short* bz = wkvT + (size_t)(nt*16 + 480 + col)*CS_;
    #pragma unroll
    for (int k = 0; k < CS_; k += 32) {
      bf16x8 a = cvt8(arow + k + g*8);
      ax = __builtin_amdgcn_mfma_f32_16x16x32_bf16(a, *(const bf16x8*)(bx + k + g*8), ax, 0,0,0);
      ay = __builtin_amdgcn_mfma_f32_16x16x32_bf16(a, *(const bf16x8*)(by + k + g*8), ay, 0,0,0);
      az = __builtin_amdgcn_mfma_f32_16x16x32_bf16(a, *(const bf16x8*)(bz + k + g*8), az, 0,0,0);
    }

    int p = nt*16 + col;
    int h = p / PKV_, pp = p % PKV_;
    #pragma unroll
    for (int r = 0; r < 4; ++r) {
      int row = row0 + g*4 + r;
      const float* R  = r2_rot   + (size_t)row*9;
      const float* tr = r2_trans + (size_t)row*3;
      float x = ax[r], y = ay[r], z = az[r];
      float g0 = R[0]*x + R[1]*y + R[2]*z + tr[0];
      float g1 = R[3]*x + R[4]*y + R[5]*z + tr[1];
      float g2 = R[6]*x + R[7]*y + R[8]*z + tr[2];
      int b = row >> 9, j = row & (N2_-1);
      int bh = b*H_ + h;
      if (pp < PQ_) {
        size_t base = ((size_t)bh*N2_ + j)*32 + pp*3;
        kgb[base]   = f2bf(g0);
        kgb[base+1] = f2bf(g1);
        kgb[base+2] = f2bf(g2);
        if (pp == 0) {
          uint4 z4 = {0u,0u,0u,0u};
          *(uint4*)(kgb + ((size_t)bh*N2_ + j)*32 + 24) = z4;
        }
        atomicAdd(&kn[(size_t)bh*N2_ + j], g0*g0 + g1*g1 + g2*g2);
      } else {
        int comp = (pp - PQ_)*3;
        size_t base = ((size_t)bh*48 + comp)*512 + j;
        vtb[base]        = f2bf(g0);
        vtb[base + 512]  = f2bf(g1);
        vtb[base + 1024] = f2bf(g2);
      }
    }
  }
}

// ---------------- MFMA flash attention, 2-way j-split ----------------
// 256 thr = 4 waves; waves (0,1) own i-tile 0, (2,3) own i-tile 1 of this
// block; within a pair, wave handles j-half (4 jt of 64 j). Linear partials
// merged through LDS; epilogue by the even wave of each pair.
#define RSTRIDE 72
#define OSTRIDE 52
__global__ __launch_bounds__(256) void attn_kernel(
    const unsigned short* __restrict__ qgb, const float* __restrict__ qn,
    const unsigned short* __restrict__ kgb, const unsigned short* __restrict__ vtb,
    const float* __restrict__ kn, const float* __restrict__ mask1,
    const float* __restrict__ mask2, const float* __restrict__ hwts,
    const float* __restrict__ rot, const float* __restrict__ trans,
    unsigned short* __restrict__ featsb)
{
  __shared__ __align__(16) unsigned short pstrip[4][16][RSTRIDE];
  __shared__ float o_s[4][16][OSTRIDE];
  __shared__ float l_s[4][16];

  int wave = threadIdx.x >> 6;
  int lane = threadIdx.x & 63;
  int col = lane & 15, g = lane >> 4;
  int pair = wave >> 1, half = wave & 1;
  int mt = blockIdx.x*2 + pair;        // i-tile id 0..3071
  int bh = mt >> 7;
  int it = mt & 127;
  int b = bh / H_, h = bh - b*H_;

  float hw = logf(1.0f + __expf(hwts[h])) * HW_SCALE_;

  bf16x8 qa = *(const bf16x8*)(qgb + (((size_t)bh*N1_ + it*16 + col)*32 + g*8));

  float ar[4], m1r[4];
  #pragma unroll
  for (int r = 0; r < 4; ++r) {
    int ig = it*16 + g*4 + r;
    ar[r]  = fmaf(-0.5f*hw, qn[(size_t)bh*N1_ + ig], -INF_);
    m1r[r] = mask1[b*N1_ + ig] * INF_;
  }

  f32x4 ot[3];
  #pragma unroll
  for (int m = 0; m < 3; ++m) ot[m] = (f32x4){0.f,0.f,0.f,0.f};
  float l[4] = {0.f,0.f,0.f,0.f};

  const unsigned short* kbase = kgb + (size_t)bh*N2_*32;
  const unsigned short* vbase = vtb + (size_t)bh*48*512;
  const float* knp = kn + (size_t)bh*N2_;
  const float* m2p = mask2 + b*N2_;

  for (int jt = half*4; jt < half*4 + 4; ++jt) {
    int j0 = jt*64;
    #pragma unroll
    for (int nt = 0; nt < 4; ++nt) {
      int jg = j0 + nt*16 + col;
      bf16x8 kb = *(const bf16x8*)(kbase + ((size_t)jg*32 + g*8));
      f32x4 dotv = __builtin_amdgcn_mfma_f32_16x16x32_bf16(
          qa, kb, (f32x4){0.f,0.f,0.f,0.f}, 0, 0, 0);
      float bc  = -0.5f*hw*knp[jg];
      float m2c = m2p[jg];
      #pragma unroll
      for (int r = 0; r < 4; ++r) {
        float logit = fmaf(hw, dotv[r], fmaf(m1r[r], m2c, ar[r] + bc));
        float w = __expf(logit);
        l[r] += w;
        pstrip[wave][g*4 + r][nt*16 + col] = f2bf(w);
      }
    }
    #pragma unroll
    for (int ks = 0; ks < 2; ++ks) {
      bf16x8 pb = *(const bf16x8*)&pstrip[wave][col][ks*32 + g*8];
      #pragma unroll
      for (int mtv = 0; mtv < 3; ++mtv) {
        bf16x8 va = *(const bf16x8*)(vbase +
            ((size_t)(mtv*16 + col))*512 + j0 + ks*32 + g*8);
        ot[mtv] = __builtin_amdgcn_mfma_f32_16x16x32_bf16(va, pb, ot[mtv], 0, 0, 0);
      }
    }
  }

  // per-wave: reduce l over the 16 cols, stash partials in LDS
  #pragma unroll
  for (int r = 0; r < 4; ++r) {
    l[r] += __shfl_xor(l[r], 1);
    l[r] += __shfl_xor(l[r], 2);
    l[r] += __shfl_xor(l[r], 4);
    l[r] += __shfl_xor(l[r], 8);
  }
  if (col == 0) {
    #pragma unroll
    for (int r = 0; r < 4; ++r) l_s[wave][g*4 + r] = l[r];
  }
  #pragma unroll
  for (int mtv = 0; mtv < 3; ++mtv)
    #pragma unroll
    for (int r = 0; r < 4; ++r)
      o_s[wave][col][mtv*16 + g*4 + r] = ot[mtv][r];
  __syncthreads();
  if (half) return;

  // even wave of each pair: merge the two j-halves and run the epilogue
  float inv = 1.0f / (l_s[wave][col] + l_s[wave+1][col]);
  int ig = it*16 + col;
  int row = b*N1_ + ig;
  const float* R  = rot   + (size_t)row*9;
  const float* tr = trans + (size_t)row*3;
  float R00=R[0],R01=R[1],R02=R[2],R10=R[3],R11=R[4],R12=R[5],R20=R[6],R21=R[7],R22=R[8];
  float t0=tr[0], t1=tr[1], t2=tr[2];
  unsigned short* fb = featsb + (size_t)row*576 + h*PV_;
  #pragma unroll
  for (int p = 0; p < 3; ++p) {
    int pt = g*3 + p;
    float ox = (o_s[wave][col][pt*3+0] + o_s[wave+1][col][pt*3+0])*inv - t0;
    float oy = (o_s[wave][col][pt*3+1] + o_s[wave+1][col][pt*3+1])*inv - t1;
    float oz = (o_s[wave][col][pt*3+2] + o_s[wave+1][col][pt*3+2])*inv - t2;
    float lx = R00*ox + R10*oy + R20*oz;
    float ly = R01*ox + R11*oy + R21*oz;
    float lz = R02*ox + R12*oy + R22*oz;
    float dist = sqrtf(lx*lx + ly*ly + lz*lz + 1e-8f);
    fb[pt]       = f2bf(lx);
    fb[144 + pt] = f2bf(ly);
    fb[288 + pt] = f2bf(lz);
    fb[432 + pt] = f2bf(dist);
  }
}

// ---------------- Output projection via MFMA, 2-way k-split ----------------
// 1024 thr = 16 waves: wave = (kh<<3)|nw; nw -> 48-col tile, kh -> k-half.
// kh=1 partials merged through LDS into kh=0's accumulators.
__global__ __launch_bounds__(1024) void outproj_mfma(
    const unsigned short* __restrict__ featsb, const unsigned short* __restrict__ woutT,
    const float* __restrict__ bout, float* __restrict__ out)
{
  __shared__ float acc_s[8][16][48];   // 24576 B
  int wave = threadIdx.x >> 6, lane = threadIdx.x & 63;
  int col = lane & 15, g = lane >> 4;
  int nw = wave & 7, kh = wave >> 3;
  int i0 = blockIdx.x * 16;
  int n0 = nw * 48;

  f32x4 acc[3];
  #pragma unroll
  for (int m = 0; m < 3; ++m) acc[m] = (f32x4){0.f,0.f,0.f,0.f};
  const unsigned short* arow = featsb + (size_t)(i0 + col)*576 + kh*288;
  const unsigned short* b0 = woutT + (size_t)(n0      + col)*576 + kh*288;
  const unsigned short* b1 = woutT + (size_t)(n0 + 16 + col)*576 + kh*288;
  const unsigned short* b2 = woutT + (size_t)(n0 + 32 + col)*576 + kh*288;
  #pragma unroll 3
  for (int k = 0; k < 288; k += 32) {
    bf16x8 a = *(const bf16x8*)(arow + k + g*8);
    acc[0] = __builtin_amdgcn_mfma_f32_16x16x32_bf16(a, *(const bf16x8*)(b0 + k + g*8), acc[0], 0,0,0);
    acc[1] = __builtin_amdgcn_mfma_f32_16x16x32_bf16(a, *(const bf16x8*)(b1 + k + g*8), acc[1], 0,0,0);
    acc[2] = __builtin_amdgcn_mfma_f32_16x16x32_bf16(a, *(const bf16x8*)(b2 + k + g*8), acc[2], 0,0,0);
  }
  if (kh) {
    #pragma unroll
    for (int t3 = 0; t3 < 3; ++t3)
      #pragma unroll
      for (int r = 0; r < 4; ++r)
        acc_s[nw][g*4 + r][t3*16 + col] = acc[t3][r];
  }
  __syncthreads();
  if (kh) return;
  #pragma unroll
  for (int t3 = 0; t3 < 3; ++t3) {
    int n = n0 + t3*16 + col;
    float bb = bout[n];
    #pragma unroll
    for (int r = 0; r < 4; ++r) {
      int row = i0 + g*4 + r;
      out[(size_t)row*CS_ + n] = acc[t3][r] + acc_s[nw][g*4 + r][t3*16 + col] + bb;
    }
  }
}

extern "C" void kernel_launch(void* const* d_in, const int* in_sizes, int n_in,
                              void* d_out, int out_size, void* d_ws, size_t ws_size,
                              hipStream_t stream) {
  const float* s1       = (const float*)d_in[0];
  const float* s2       = (const float*)d_in[1];
  const float* r1_rot   = (const float*)d_in[2];
  const float* r1_trans = (const float*)d_in[3];
  const float* r2_rot   = (const float*)d_in[4];
  const float* r2_trans = (const float*)d_in[5];
  const float* mask1    = (const float*)d_in[6];
  const float* mask2    = (const float*)d_in[7];
  const float* Wq       = (const float*)d_in[8];
  const float* Wkv      = (const float*)d_in[9];
  const float* hwts     = (const float*)d_in[10];
  const float* Wout     = (const float*)d_in[11];
  const float* bout     = (const float*)d_in[12];
  float* out = (float*)d_out;

  float* qn = (float*)d_ws;                              // 49152 f32
  float* kn = qn + (size_t)B_*H_*N1_;                    // 12288 f32
  unsigned short* featsb = (unsigned short*)(kn + (size_t)B_*H_*N2_); // 2359296 u16
  unsigned short* qgb  = featsb + (size_t)B_*N1_*576;    // 1572864 u16
  unsigned short* kgb  = qgb  + (size_t)B_*H_*N1_*32;    // 393216 u16
  unsigned short* vtb  = kgb  + (size_t)B_*H_*N2_*32;    // 589824 u16
  unsigned short* wqT  = vtb  + (size_t)B_*H_*48*512;    // 110592 u16
  unsigned short* wkvT = wqT  + (size_t)CQ_*CS_;         // 276480 u16
  unsigned short* woutT= wkvT + (size_t)CKV_*CS_;        // 221184 u16

  prep_kernel<<<TQ_+TKV_+TWO_+VPAD_+KN_, 256, 0, stream>>>(
      Wq, Wkv, Wout, wqT, wkvT, woutT, vtb, kn);
  proj_mfma<<<624, 256, 0, stream>>>(s1, s2, wqT, wkvT, r1_rot, r1_trans,
                                     r2_rot, r2_trans, qgb, qn, kgb, vtb, kn);
  attn_kernel<<<B_*H_*(N1_/32), 256, 0, stream>>>(qgb, qn, kgb, vtb, kn, mask1, mask2,
                                                  hwts, r1_rot, r1_trans, featsb);
  outproj_mfma<<<256, 1024, 0, stream>>>(featsb, woutT, bout, out);
}